// Round 15
// baseline (173.744 us; speedup 1.0000x reference)
//
#include <hip/hip_runtime.h>
#include <hip/hip_bf16.h>

using bf16 = __hip_bfloat16;
typedef __attribute__((ext_vector_type(8))) __bf16 bf16x8;
typedef __attribute__((ext_vector_type(4))) float f32x4;

namespace {

constexpr int D     = 256;
constexpr int NTOK  = 32768;   // B*L
constexpr int NSLOT = 8192;    // B*N
constexpr int GG    = 64;
constexpr int KK    = 16;
constexpr int NN    = 1024;

// Abramowitz–Stegun 7.1.26 rational erf, |err| <= 1.5e-7
__device__ __forceinline__ float erf_fast(float x){
  const float ax = fabsf(x);
  const float tt = 1.0f / fmaf(0.3275911f, ax, 1.0f);
  float p = fmaf(1.061405429f, tt, -1.453152027f);
  p = fmaf(p, tt, 1.421413741f);
  p = fmaf(p, tt, -0.284496736f);
  p = fmaf(p, tt, 0.254829592f);
  p *= tt;
  const float e = __expf(-ax*ax);
  const float r = 1.0f - p*e;
  return copysignf(r, x);
}

__device__ __forceinline__ float gelu_f(float x){
  return 0.5f * x * (1.0f + erf_fast(x * 0.70710678118654752f));
}

struct alignas(16) ushort8s { unsigned short v[8]; };

__device__ __forceinline__ ushort8s pack8(const float* src){
  const float4 f0 = reinterpret_cast<const float4*>(src)[0];
  const float4 f1 = reinterpret_cast<const float4*>(src)[1];
  ushort8s u;
  u.v[0] = __bfloat16_as_ushort(__float2bfloat16(f0.x));
  u.v[1] = __bfloat16_as_ushort(__float2bfloat16(f0.y));
  u.v[2] = __bfloat16_as_ushort(__float2bfloat16(f0.z));
  u.v[3] = __bfloat16_as_ushort(__float2bfloat16(f0.w));
  u.v[4] = __bfloat16_as_ushort(__float2bfloat16(f1.x));
  u.v[5] = __bfloat16_as_ushort(__float2bfloat16(f1.y));
  u.v[6] = __bfloat16_as_ushort(__float2bfloat16(f1.z));
  u.v[7] = __bfloat16_as_ushort(__float2bfloat16(f1.w));
  return u;
}

// ---------------------------------------------------------------------------
// Fragment-packed layout: logical Wt[N][K] bf16 stored as 1KB tiles
//   flat = ((ng*NK + kt)*64 + fRow*4 + kq)*8 + e
// A wave's fragment load for (ng, kt) is ONE contiguous 1KB read.
// ---------------------------------------------------------------------------

__global__ void prep_w_k(const float* __restrict__ Wm1, const float* __restrict__ Wg1,
                         const float* __restrict__ Wm2, const float* __restrict__ Wu1,
                         const float* __restrict__ Wu2, const float* __restrict__ Wgr,
                         const float* __restrict__ Wsl, const float* __restrict__ bm1,
                         const float* __restrict__ bg1,
                         bf16* __restrict__ W1p, bf16* __restrict__ W2p,
                         bf16* __restrict__ Wu1p, bf16* __restrict__ Wu2p,
                         float* __restrict__ Wcat, float* __restrict__ bcat)
{
  const int idx = blockIdx.x*256 + threadIdx.x;
  if (idx < 196608){                                    // W1cat packed, NK=8
    const int e = idx&7, q = (idx>>3)&3, f = (idx>>5)&15, tile = idx>>9;
    const int kt = tile&7, ng = tile>>3;
    const int n = ng*16+f, k = kt*32+q*8+e;
    W1p[idx] = __float2bfloat16(n < 512 ? Wm1[k*512+n] : Wg1[k*256+(n-512)]);
  } else if (idx < 327680){                             // Wm2 packed, NK=16
    const int i = idx-196608;
    const int e = i&7, q = (i>>3)&3, f = (i>>5)&15, tile = i>>9;
    const int kt = tile&15, ng = tile>>4;
    W2p[i] = __float2bfloat16(Wm2[(kt*32+q*8+e)*256 + ng*16+f]);
  } else if (idx < 589824){                             // Wu1 packed, NK=16
    const int i = idx-327680;
    const int e = i&7, q = (i>>3)&3, f = (i>>5)&15, tile = i>>9;
    const int kt = tile&15, ng = tile>>4;
    Wu1p[i] = __float2bfloat16(Wu1[(kt*32+q*8+e)*512 + ng*16+f]);
  } else if (idx < 720896){                             // Wu2 packed, NK=16
    const int i = idx-589824;
    const int e = i&7, q = (i>>3)&3, f = (i>>5)&15, tile = i>>9;
    const int kt = tile&15, ng = tile>>4;
    Wu2p[i] = __float2bfloat16(Wu2[(kt*32+q*8+e)*256 + ng*16+f]);
  } else if (idx < 741376){                             // Wcat [256][80] fp32 (k-major)
    const int i = idx - 720896, k = i / 80, c = i - k*80;
    Wcat[i] = (c < GG) ? Wgr[k*GG + c] : Wsl[k*KK + (c - GG)];
  } else if (idx < 742144){                             // bcat [768]
    const int c = idx - 741376;
    bcat[c] = (c < 512) ? bm1[c] : bg1[c - 512];
  }
}

// X (32768x256 f32) -> packed bf16, NK=8.
__global__ void cvt_pack_x_k(const float* __restrict__ X, bf16* __restrict__ Xp){
  const int chunk = blockIdx.x*256 + threadIdx.x;       // over 1048576
  const int q = chunk&3, f = (chunk>>2)&15, tile = chunk>>6;
  const int kt = tile&7, ng = tile>>3;
  const float* src = X + (size_t)(ng*16+f)*256 + kt*32 + q*8;
  reinterpret_cast<ushort8s*>(Xp)[chunk] = pack8(src);
}

// H = [S | inc] (8192x512 f32 logical) -> packed bf16, NK=16.
__global__ void pack_h_k(const float* __restrict__ S, const float* __restrict__ inc,
                         bf16* __restrict__ Hp){
  const int chunk = blockIdx.x*256 + threadIdx.x;       // over 524288
  const int q = chunk&3, f = (chunk>>2)&15, tile = chunk>>6;
  const int kt = tile&15, ng = tile>>4;
  const int r = ng*16+f, c = kt*32+q*8;
  const float* src = (c < 256) ? (S + (size_t)r*256 + c) : (inc + (size_t)r*256 + (c-256));
  reinterpret_cast<ushort8s*>(Hp)[chunk] = pack8(src);
}

// ---------------------------------------------------------------------------
// Fused kernel, fragment-packed operands.
// EPI=2 (msg): [phase R: fp32 routing for the block's 64 tokens -> slot_lds
//               (replaces route4_k; X/Wcat chunks staged in the H1 LDS region,
//               identical accumulation order + first-win argmax)]
//              then H1 = gelu(X@W1cat+b1) (512 cols -> LDS swizzled; 256 gate
//              cols -> dot Wg2 -> gate_lds), C = H1@W2+b2,
//              scatter: inc[slot] += (C+b2)*sigmoid(gate).
// EPI=1 (upd): C + S residual + LayerNorm -> f32 out.
// ---------------------------------------------------------------------------
template<int K, int N1, int NG, int N2, int BM, int EPI>
__global__ __launch_bounds__(512, 2) void fused2_k(
    const bf16* __restrict__ Ap,
    const bf16* __restrict__ W1p, const float* __restrict__ b1,
    const bf16* __restrict__ W2p, const float* __restrict__ b2,
    void* __restrict__ Cout,
    const float* __restrict__ S, const float* __restrict__ lnw, const float* __restrict__ lnb,
    const float* __restrict__ Wg2,
    const float* __restrict__ Xf, const float* __restrict__ Wcat,
    const float* __restrict__ bg2p, float* __restrict__ incp)
{
  constexpr int SLICE = (N1 + NG) / 8;  // cols per wave, phase A (96 or 64)
  constexpr int SP    = SLICE / 32;     // 32-col sub-phases
  constexpr int MF    = BM / 16;        // M fragments (4 or 2)
  constexpr int NKA   = K / 32;
  constexpr int NKB   = N1 / 32;
  constexpr int H1B   = BM * N1 * 2;    // LDS bytes for H1
  __shared__ alignas(16) char smem[H1B];
  __shared__ float gate_lds[EPI == 2 ? BM : 1];
  __shared__ int   slot_lds[EPI == 2 ? BM : 1];

  const int t = threadIdx.x, lane = t & 63, w = t >> 6;
  const int fRow = lane & 15, kq = lane >> 4, kOff = kq * 8;
  const int lo8 = (fRow*4 + kq) * 8;    // per-lane elem offset within a 1KB tile
  const int bm0 = blockIdx.x * BM;

  f32x4 acc[MF][2];                     // single accumulator, reused by phase B

  if constexpr (EPI == 2){
    // ---------- phase R: routing for this block's BM tokens ----------
    float* Xc = (float*)smem;                   // [16][68] fp32 X chunk (transposed)
    float* Wc = (float*)(smem + 4352);          // [16][80] fp32 Wcat chunk
    const int cq = t & 15, tg = t >> 4;         // tg 0..31 -> tokens tg*2, tg*2+1
    float ag0[4] = {0.f,0.f,0.f,0.f}, ag1[4] = {0.f,0.f,0.f,0.f};
    float as0 = 0.f, as1 = 0.f;
    for (int kt16 = 0; kt16 < 16; ++kt16){
      __syncthreads();                          // prev compute done, safe to restage
      if (t < 256){
        const int tok = t >> 2, q4 = (t & 3) * 4;
        const float4 xv = *reinterpret_cast<const float4*>(
            Xf + (size_t)(bm0 + tok)*256 + kt16*16 + q4);
        Xc[(q4+0)*68 + tok] = xv.x;
        Xc[(q4+1)*68 + tok] = xv.y;
        Xc[(q4+2)*68 + tok] = xv.z;
        Xc[(q4+3)*68 + tok] = xv.w;
      } else {
        const int c2 = t - 256;
#pragma unroll
        for (int j = 0; j < 5; ++j){
          const int flat = c2*5 + j;
          Wc[flat] = Wcat[kt16*1280 + flat];
        }
      }
      __syncthreads();
#pragma unroll
      for (int k = 0; k < 16; ++k){
        const float x0 = Xc[k*68 + tg*2], x1 = Xc[k*68 + tg*2 + 1];
        const float4 wq = *reinterpret_cast<const float4*>(&Wc[k*80 + 4*cq]);
        const float wsv = Wc[k*80 + 64 + cq];
        ag0[0] = fmaf(x0, wq.x, ag0[0]); ag0[1] = fmaf(x0, wq.y, ag0[1]);
        ag0[2] = fmaf(x0, wq.z, ag0[2]); ag0[3] = fmaf(x0, wq.w, ag0[3]);
        ag1[0] = fmaf(x1, wq.x, ag1[0]); ag1[1] = fmaf(x1, wq.y, ag1[1]);
        ag1[2] = fmaf(x1, wq.z, ag1[2]); ag1[3] = fmaf(x1, wq.w, ag1[3]);
        as0 = fmaf(x0, wsv, as0); as1 = fmaf(x1, wsv, as1);
      }
    }
    __syncthreads();
    float* Cs = (float*)smem;                   // [64][84] logits
#pragma unroll
    for (int j = 0; j < 4; ++j){
      Cs[(tg*2+0)*84 + 4*cq + j] = ag0[j];
      Cs[(tg*2+1)*84 + 4*cq + j] = ag1[j];
    }
    Cs[(tg*2+0)*84 + 64 + cq] = as0;
    Cs[(tg*2+1)*84 + 64 + cq] = as1;
    __syncthreads();
    if (t < BM){
      const float* row = &Cs[t*84];
      float bg = row[0]; int big = 0;
      for (int g = 1; g < 64; ++g){ const float v = row[g]; if (v > bg){ bg = v; big = g; } }
      float bs = row[64]; int bis = 0;
      for (int s2 = 1; s2 < 16; ++s2){ const float v = row[64+s2]; if (v > bs){ bs = v; bis = s2; } }
      slot_lds[t] = big * KK + bis;
      gate_lds[t] = 0.f;
    }
    __syncthreads();                            // smem now free for H1
  }

  // ---------------- phase A ----------------
  for (int sp = 0; sp < SP; ++sp){
    const int colb = w * SLICE + sp * 32;
    const bf16* bp0 = W1p + ((size_t)((colb>>4)    ) * NKA) * 512 + lo8;
    const bf16* bp1 = W1p + ((size_t)((colb>>4) + 1) * NKA) * 512 + lo8;

#pragma unroll
    for (int mf = 0; mf < MF; ++mf)
#pragma unroll
      for (int j = 0; j < 2; ++j)
#pragma unroll
        for (int r = 0; r < 4; ++r) acc[mf][j][r] = 0.f;

#pragma unroll
    for (int kt = 0; kt < NKA; ++kt){
      const bf16x8 b0  = *reinterpret_cast<const bf16x8*>(bp0 + kt*512);
      const bf16x8 b1v = *reinterpret_cast<const bf16x8*>(bp1 + kt*512);
#pragma unroll
      for (int mf = 0; mf < MF; ++mf){
        const bf16x8 a = *reinterpret_cast<const bf16x8*>(
            Ap + ((size_t)((bm0>>4) + mf) * NKA + kt) * 512 + lo8);
        acc[mf][0] = __builtin_amdgcn_mfma_f32_16x16x32_bf16(a, b0,  acc[mf][0], 0, 0, 0);
        acc[mf][1] = __builtin_amdgcn_mfma_f32_16x16x32_bf16(a, b1v, acc[mf][1], 0, 0, 0);
      }
    }

    // sub-phase epilogue: H1 write (swizzled) or gate accumulation into LDS
    if (NG == 0 || colb < N1){
#pragma unroll
      for (int mf = 0; mf < MF; ++mf){
#pragma unroll
        for (int j = 0; j < 2; ++j){
          const int col = colb + j*16 + fRow;
          const float bvx = b1[col];
#pragma unroll
          for (int r = 0; r < 4; ++r){
            const int row = mf*16 + kq*4 + r;
            const float v = gelu_f(acc[mf][j][r] + bvx);
            const unsigned off = ((unsigned)(row*N1 + col)*2u) ^ ((unsigned)(row & 7) << 4);
            *(bf16*)(smem + off) = __float2bfloat16(v);
          }
        }
      }
    } else if constexpr (NG > 0 && EPI == 2){
      const float b1v0 = b1[colb + fRow],       b1v1 = b1[colb + 16 + fRow];
      const float wg0  = Wg2[colb - N1 + fRow], wg1  = Wg2[colb - N1 + 16 + fRow];
#pragma unroll
      for (int mf = 0; mf < MF; ++mf){
#pragma unroll
        for (int r = 0; r < 4; ++r){
          float p = gelu_f(acc[mf][0][r] + b1v0) * wg0
                  + gelu_f(acc[mf][1][r] + b1v1) * wg1;
          p += __shfl_xor(p, 1); p += __shfl_xor(p, 2);
          p += __shfl_xor(p, 4); p += __shfl_xor(p, 8);
          if (fRow == 0) atomicAdd(&gate_lds[mf*16 + kq*4 + r], p);
        }
      }
    }
  }
  __syncthreads();   // H1 + gate partials complete, visible to all waves

  if constexpr (EPI == 2){
    if (t < BM) gate_lds[t] = 1.f / (1.f + __expf(-(gate_lds[t] + bg2p[0])));
  }

  // ---------------- phase B: C = H1 @ W2 + b2 ----------------
  const int colb2 = w * (N2 / 8);
  const bf16* cp0 = W2p + ((size_t)((colb2>>4)    ) * NKB) * 512 + lo8;
  const bf16* cp1 = W2p + ((size_t)((colb2>>4) + 1) * NKB) * 512 + lo8;

#pragma unroll
  for (int mf = 0; mf < MF; ++mf)
#pragma unroll
    for (int j = 0; j < 2; ++j)
#pragma unroll
      for (int r = 0; r < 4; ++r) acc[mf][j][r] = 0.f;

#pragma unroll
  for (int kt = 0; kt < NKB; ++kt){
    const bf16x8 c0 = *reinterpret_cast<const bf16x8*>(cp0 + kt*512);
    const bf16x8 c1 = *reinterpret_cast<const bf16x8*>(cp1 + kt*512);
#pragma unroll
    for (int mf = 0; mf < MF; ++mf){
      const int row = mf*16 + fRow;
      const unsigned off = ((unsigned)(row*N1 + kt*32 + kOff)*2u) ^ ((unsigned)(row & 7) << 4);
      const bf16x8 af = *reinterpret_cast<const bf16x8*>(smem + off);
      acc[mf][0] = __builtin_amdgcn_mfma_f32_16x16x32_bf16(af, c0, acc[mf][0], 0, 0, 0);
      acc[mf][1] = __builtin_amdgcn_mfma_f32_16x16x32_bf16(af, c1, acc[mf][1], 0, 0, 0);
    }
  }

  if constexpr (EPI == 2){
    // scatter epilogue: inc[(b*NN + slot[tok])*D + col] += (C + b2) * gate
    __syncthreads();                    // gate_lds sigmoid + all H1 reads done
    const int bb = bm0 >> 12;           // batch (BM divides 4096)
#pragma unroll
    for (int mf = 0; mf < MF; ++mf){
      float gr[4]; int sl[4];
#pragma unroll
      for (int r = 0; r < 4; ++r){
        const int row = mf*16 + kq*4 + r;
        gr[r] = gate_lds[row];
        sl[r] = slot_lds[row];
      }
#pragma unroll
      for (int j = 0; j < 2; ++j){
        const int col = colb2 + j*16 + fRow;
        const float bvx = b2[col];
#pragma unroll
        for (int r = 0; r < 4; ++r)
          atomicAdd(incp + ((size_t)(bb*NN + sl[r]))*D + col, (acc[mf][j][r] + bvx) * gr[r]);
      }
    }
  } else {
    // fused residual + LayerNorm (BM=32, rows complete across the 8 waves' cols)
    float vals[MF][2][4];
#pragma unroll
    for (int mf = 0; mf < MF; ++mf){
      const int row0 = mf*16 + kq*4;
#pragma unroll
      for (int j = 0; j < 2; ++j){
        const int col = colb2 + j*16 + fRow;
        const float bvx = b2[col];
#pragma unroll
        for (int r = 0; r < 4; ++r)
          vals[mf][j][r] = S[(size_t)(bm0 + row0 + r)*N2 + col] + acc[mf][j][r] + bvx;
      }
    }
    __syncthreads();                    // all H1 reads done; smem reusable
    float* red = (float*)smem;          // [BM rows][8 waves][2]
#pragma unroll
    for (int mf = 0; mf < MF; ++mf)
#pragma unroll
      for (int r = 0; r < 4; ++r){
        float s = 0.f, q = 0.f;
#pragma unroll
        for (int j = 0; j < 2; ++j){ s += vals[mf][j][r]; q += vals[mf][j][r]*vals[mf][j][r]; }
        s += __shfl_xor(s, 1); s += __shfl_xor(s, 2); s += __shfl_xor(s, 4); s += __shfl_xor(s, 8);
        q += __shfl_xor(q, 1); q += __shfl_xor(q, 2); q += __shfl_xor(q, 4); q += __shfl_xor(q, 8);
        if (fRow == 0){
          const int row = mf*16 + kq*4 + r;
          red[(row*8 + w)*2 + 0] = s;
          red[(row*8 + w)*2 + 1] = q;
        }
      }
    __syncthreads();
    float* mur = (float*)smem + BM*8*2;
    if (t < BM){
      float s = 0.f, q = 0.f;
      for (int w2 = 0; w2 < 8; w2++){ s += red[(t*8 + w2)*2]; q += red[(t*8 + w2)*2 + 1]; }
      const float mu = s * (1.f/256.f);
      const float var = q * (1.f/256.f) - mu*mu;
      mur[t*2] = mu; mur[t*2 + 1] = rsqrtf(var + 1e-5f);
    }
    __syncthreads();
#pragma unroll
    for (int mf = 0; mf < MF; ++mf){
      const int row0 = mf*16 + kq*4;
#pragma unroll
      for (int j = 0; j < 2; ++j){
        const int col = colb2 + j*16 + fRow;
        const float lw = lnw[col], lb = lnb[col];
#pragma unroll
        for (int r = 0; r < 4; ++r){
          const int row = row0 + r;
          ((float*)Cout)[(size_t)(bm0 + row)*N2 + col] =
              (vals[mf][j][r] - mur[row*2]) * mur[row*2 + 1] * lw + lb;
        }
      }
    }
  }
}

} // namespace

extern "C" void kernel_launch(void* const* d_in, const int* in_sizes, int n_in,
                              void* d_out, int out_size, void* d_ws, size_t ws_size,
                              hipStream_t stream)
{
  (void)in_sizes; (void)n_in; (void)out_size; (void)ws_size;
  const float* X   = (const float*)d_in[0];
  const float* S   = (const float*)d_in[1];
  const float* Wgr = (const float*)d_in[2];
  const float* Wsl = (const float*)d_in[3];
  const float* Wm1 = (const float*)d_in[4];
  const float* bm1 = (const float*)d_in[5];
  const float* Wm2 = (const float*)d_in[6];
  const float* bm2 = (const float*)d_in[7];
  const float* Wg1 = (const float*)d_in[8];
  const float* bg1 = (const float*)d_in[9];
  const float* Wg2 = (const float*)d_in[10];
  const float* bg2 = (const float*)d_in[11];
  const float* Wu1 = (const float*)d_in[12];
  const float* bu1 = (const float*)d_in[13];
  const float* Wu2 = (const float*)d_in[14];
  const float* bu2 = (const float*)d_in[15];
  const float* lnw = (const float*)d_in[16];
  const float* lnb = (const float*)d_in[17];
  float* out = (float*)d_out;

  char* ws = (char*)d_ws;
  bf16* Xp   = (bf16*)(ws + 0);                   // 16,777,216 B (packed X)
  bf16* Hp   = (bf16*)(ws + 16777216);            //  8,388,608 B (packed [S|inc])
  bf16* W1p  = (bf16*)(ws + 67108864);            // 393,216 B (packed [Wm1|Wg1], NK=8)
  bf16* W2p  = (bf16*)(ws + 67108864 + 393216);   // 262,144 B (packed Wm2, NK=16)
  bf16* Wu1p = (bf16*)(ws + 67108864 + 655360);   // 524,288 B (packed Wu1, NK=16)
  bf16* Wu2p = (bf16*)(ws + 67108864 + 1179648);  // 262,144 B (packed Wu2, NK=16)
  float* inc  = (float*)(ws + 68812800);          // 8,388,608 B
  float* Wcat = (float*)(ws + 77201408);          // 81,920 B
  float* bcat = (float*)(ws + 77201408 + 81920);  // 3,072 B

  prep_w_k<<<(742144 + 255)/256, 256, 0, stream>>>(Wm1, Wg1, Wm2, Wu1, Wu2, Wgr, Wsl, bm1, bg1,
                                                   W1p, W2p, Wu1p, Wu2p, Wcat, bcat);
  cvt_pack_x_k<<<4096, 256, 0, stream>>>(X, Xp);
  hipMemsetAsync(inc, 0, (size_t)NSLOT*D*sizeof(float), stream);

  // fused route + msg MLP + gate + scatter:
  //   slot = argmax routing (in-block); inc[slot] += (gelu(X@Wm1+bm1)@Wm2+bm2)*sigmoid(gate)
  fused2_k<256, 512, 256, 256, 64, 2><<<NTOK/64, 512, 0, stream>>>(
      Xp, W1p, bcat, W2p, bm2, nullptr,
      nullptr, nullptr, nullptr, Wg2, X, Wcat, bg2, inc);

  // pack H = [S | inc] into fragment order for the update MLP
  pack_h_k<<<2048, 256, 0, stream>>>(S, inc, Hp);

  // fused slot-update MLP + residual + LayerNorm -> out
  fused2_k<512, 512, 0, 256, 32, 1><<<NSLOT/32, 512, 0, stream>>>(
      Hp, Wu1p, bu1, Wu2p, bu2, out,
      S, lnw, lnb, nullptr, nullptr, nullptr, nullptr, nullptr);
}

// Round 17
// 150.483 us; speedup vs baseline: 1.1546x; 1.1546x over previous
//
#include <hip/hip_runtime.h>
#include <hip/hip_bf16.h>

using bf16 = __hip_bfloat16;
typedef __attribute__((ext_vector_type(8))) __bf16 bf16x8;
typedef __attribute__((ext_vector_type(4))) float f32x4;

namespace {

constexpr int D     = 256;
constexpr int NTOK  = 32768;   // B*L
constexpr int NSLOT = 8192;    // B*N
constexpr int GG    = 64;
constexpr int KK    = 16;
constexpr int NN    = 1024;

// Abramowitz–Stegun 7.1.26 rational erf, |err| <= 1.5e-7
__device__ __forceinline__ float erf_fast(float x){
  const float ax = fabsf(x);
  const float tt = 1.0f / fmaf(0.3275911f, ax, 1.0f);
  float p = fmaf(1.061405429f, tt, -1.453152027f);
  p = fmaf(p, tt, 1.421413741f);
  p = fmaf(p, tt, -0.284496736f);
  p = fmaf(p, tt, 0.254829592f);
  p *= tt;
  const float e = __expf(-ax*ax);
  const float r = 1.0f - p*e;
  return copysignf(r, x);
}

__device__ __forceinline__ float gelu_f(float x){
  return 0.5f * x * (1.0f + erf_fast(x * 0.70710678118654752f));
}

__device__ __forceinline__ void async_ld16(const void* g, void* l){
  typedef const __attribute__((address_space(1))) unsigned int gu32;
  typedef __attribute__((address_space(3))) unsigned int lu32;
  __builtin_amdgcn_global_load_lds((gu32*)g, (lu32*)l, 16, 0, 0);
}

struct alignas(16) ushort8s { unsigned short v[8]; };

__device__ __forceinline__ ushort8s pack8(const float* src){
  const float4 f0 = reinterpret_cast<const float4*>(src)[0];
  const float4 f1 = reinterpret_cast<const float4*>(src)[1];
  ushort8s u;
  u.v[0] = __bfloat16_as_ushort(__float2bfloat16(f0.x));
  u.v[1] = __bfloat16_as_ushort(__float2bfloat16(f0.y));
  u.v[2] = __bfloat16_as_ushort(__float2bfloat16(f0.z));
  u.v[3] = __bfloat16_as_ushort(__float2bfloat16(f0.w));
  u.v[4] = __bfloat16_as_ushort(__float2bfloat16(f1.x));
  u.v[5] = __bfloat16_as_ushort(__float2bfloat16(f1.y));
  u.v[6] = __bfloat16_as_ushort(__float2bfloat16(f1.z));
  u.v[7] = __bfloat16_as_ushort(__float2bfloat16(f1.w));
  return u;
}

// ---------------------------------------------------------------------------
// Fragment-packed layout: logical Wt[N][K] bf16 stored as 1KB tiles
//   flat = ((ng*NK + kt)*64 + fRow*4 + kq)*8 + e
// A wave's fragment load for (ng, kt) is ONE contiguous 1KB read. A block's
// whole A-tile (BM rows) is one contiguous BM*K*2-byte region -> LDS-stageable
// with linear global_load_lds.
// ---------------------------------------------------------------------------

__global__ void prep_w_k(const float* __restrict__ Wm1, const float* __restrict__ Wg1,
                         const float* __restrict__ Wm2, const float* __restrict__ Wu1,
                         const float* __restrict__ Wu2, const float* __restrict__ Wgr,
                         const float* __restrict__ Wsl, const float* __restrict__ bm1,
                         const float* __restrict__ bg1,
                         bf16* __restrict__ W1p, bf16* __restrict__ W2p,
                         bf16* __restrict__ Wu1p, bf16* __restrict__ Wu2p,
                         float* __restrict__ Wcat, float* __restrict__ bcat)
{
  const int idx = blockIdx.x*256 + threadIdx.x;
  if (idx < 196608){                                    // W1cat packed, NK=8
    const int e = idx&7, q = (idx>>3)&3, f = (idx>>5)&15, tile = idx>>9;
    const int kt = tile&7, ng = tile>>3;
    const int n = ng*16+f, k = kt*32+q*8+e;
    W1p[idx] = __float2bfloat16(n < 512 ? Wm1[k*512+n] : Wg1[k*256+(n-512)]);
  } else if (idx < 327680){                             // Wm2 packed, NK=16
    const int i = idx-196608;
    const int e = i&7, q = (i>>3)&3, f = (i>>5)&15, tile = i>>9;
    const int kt = tile&15, ng = tile>>4;
    W2p[i] = __float2bfloat16(Wm2[(kt*32+q*8+e)*256 + ng*16+f]);
  } else if (idx < 589824){                             // Wu1 packed, NK=16
    const int i = idx-327680;
    const int e = i&7, q = (i>>3)&3, f = (i>>5)&15, tile = i>>9;
    const int kt = tile&15, ng = tile>>4;
    Wu1p[i] = __float2bfloat16(Wu1[(kt*32+q*8+e)*512 + ng*16+f]);
  } else if (idx < 720896){                             // Wu2 packed, NK=16
    const int i = idx-589824;
    const int e = i&7, q = (i>>3)&3, f = (i>>5)&15, tile = i>>9;
    const int kt = tile&15, ng = tile>>4;
    Wu2p[i] = __float2bfloat16(Wu2[(kt*32+q*8+e)*256 + ng*16+f]);
  } else if (idx < 741376){                             // Wcat [256][80] fp32 (k-major)
    const int i = idx - 720896, k = i / 80, c = i - k*80;
    Wcat[i] = (c < GG) ? Wgr[k*GG + c] : Wsl[k*KK + (c - GG)];
  } else if (idx < 742144){                             // bcat [768]
    const int c = idx - 741376;
    bcat[c] = (c < 512) ? bm1[c] : bg1[c - 512];
  }
}

// X (32768x256 f32) -> packed bf16, NK=8.
__global__ void cvt_pack_x_k(const float* __restrict__ X, bf16* __restrict__ Xp){
  const int chunk = blockIdx.x*256 + threadIdx.x;       // over 1048576
  const int q = chunk&3, f = (chunk>>2)&15, tile = chunk>>6;
  const int kt = tile&7, ng = tile>>3;
  const float* src = X + (size_t)(ng*16+f)*256 + kt*32 + q*8;
  reinterpret_cast<ushort8s*>(Xp)[chunk] = pack8(src);
}

// H = [S | inc] (8192x512 f32 logical) -> packed bf16, NK=16.
__global__ void pack_h_k(const float* __restrict__ S, const float* __restrict__ inc,
                         bf16* __restrict__ Hp){
  const int chunk = blockIdx.x*256 + threadIdx.x;       // over 524288
  const int q = chunk&3, f = (chunk>>2)&15, tile = chunk>>6;
  const int kt = tile&15, ng = tile>>4;
  const int r = ng*16+f, c = kt*32+q*8;
  const float* src = (c < 256) ? (S + (size_t)r*256 + c) : (inc + (size_t)r*256 + (c-256));
  reinterpret_cast<ushort8s*>(Hp)[chunk] = pack8(src);
}

// ---------------------------------------------------------------------------
// Fused 2-layer MLP, fragment-packed operands, A-tile staged in LDS.
//   stage: As_lds <- Ap[block] (contiguous 32KB, global_load_lds, linear)
//   H1 = gelu(A@W1 + b1)   [cols < N1 -> LDS (XOR-swizzled); cols >= N1 are
//                           gate columns -> dot with Wg2, atomicAdd to gate_lds]
//   C  = H1 @ W2 + b2
// Inner-loop global loads drop 6 -> 2 per kt (A now ds_read_b128 ~12cy).
// EPI=1: C + S residual + LayerNorm -> f32 Cout (slot update).
// EPI=2: scatter epilogue — gate = sigmoid(gate_lds+bg2); atomicAdd
//        (C)*gate into inc[slot] directly.
// ---------------------------------------------------------------------------
template<int K, int N1, int NG, int N2, int BM, int EPI>
__global__ __launch_bounds__(512, 1) void fused2_k(
    const bf16* __restrict__ Ap,
    const bf16* __restrict__ W1p, const float* __restrict__ b1,
    const bf16* __restrict__ W2p, const float* __restrict__ b2,
    void* __restrict__ Cout,
    const float* __restrict__ S, const float* __restrict__ lnw, const float* __restrict__ lnb,
    const float* __restrict__ Wg2,
    const int* __restrict__ slotp, const float* __restrict__ bg2p, float* __restrict__ incp)
{
  constexpr int SLICE = (N1 + NG) / 8;  // cols per wave, phase A (96 or 64)
  constexpr int SP    = SLICE / 32;     // 32-col sub-phases
  constexpr int MF    = BM / 16;        // M fragments (4 or 2)
  constexpr int NKA   = K / 32;
  constexpr int NKB   = N1 / 32;
  constexpr int H1B   = BM * N1 * 2;    // LDS bytes for H1
  constexpr int AB    = BM * K * 2;     // LDS bytes for A tile (32KB both kernels)
  __shared__ alignas(16) char smem[H1B];
  __shared__ alignas(16) char As_lds[AB];
  __shared__ float gate_lds[EPI == 2 ? BM : 1];
  __shared__ int   slot_lds[EPI == 2 ? BM : 1];

  const int t = threadIdx.x, lane = t & 63, w = t >> 6;
  const int fRow = lane & 15, kq = lane >> 4, kOff = kq * 8;
  const int lo8 = (fRow*4 + kq) * 8;    // per-lane elem offset within a 1KB tile
  const int bm0 = blockIdx.x * BM;

  // ---- stage A tile: contiguous region in packed layout, linear LDS dest ----
  {
    const bf16* Asrc = Ap + (size_t)(bm0 >> 4) * NKA * 512;
#pragma unroll
    for (int u = t; u < AB/16; u += 512)
      async_ld16(Asrc + u*8, (bf16*)As_lds + u*8);
  }
  if constexpr (EPI == 2){
    if (t < BM){ gate_lds[t] = 0.f; slot_lds[t] = slotp[bm0 + t]; }
  }
  asm volatile("s_waitcnt vmcnt(0)" ::: "memory");
  __syncthreads();

  f32x4 acc[MF][2];                     // single accumulator, reused by phase B

  // ---------------- phase A ----------------
  for (int sp = 0; sp < SP; ++sp){
    const int colb = w * SLICE + sp * 32;
    const bf16* bp0 = W1p + ((size_t)((colb>>4)    ) * NKA) * 512 + lo8;
    const bf16* bp1 = W1p + ((size_t)((colb>>4) + 1) * NKA) * 512 + lo8;

#pragma unroll
    for (int mf = 0; mf < MF; ++mf)
#pragma unroll
      for (int j = 0; j < 2; ++j)
#pragma unroll
        for (int r = 0; r < 4; ++r) acc[mf][j][r] = 0.f;

#pragma unroll
    for (int kt = 0; kt < NKA; ++kt){
      const bf16x8 b0  = *reinterpret_cast<const bf16x8*>(bp0 + kt*512);
      const bf16x8 b1v = *reinterpret_cast<const bf16x8*>(bp1 + kt*512);
#pragma unroll
      for (int mf = 0; mf < MF; ++mf){
        const bf16x8 a = *reinterpret_cast<const bf16x8*>(
            (const bf16*)As_lds + ((mf*NKA + kt)*512 + lo8));
        acc[mf][0] = __builtin_amdgcn_mfma_f32_16x16x32_bf16(a, b0,  acc[mf][0], 0, 0, 0);
        acc[mf][1] = __builtin_amdgcn_mfma_f32_16x16x32_bf16(a, b1v, acc[mf][1], 0, 0, 0);
      }
    }

    // sub-phase epilogue: H1 write (swizzled) or gate accumulation into LDS
    if (NG == 0 || colb < N1){
#pragma unroll
      for (int mf = 0; mf < MF; ++mf){
#pragma unroll
        for (int j = 0; j < 2; ++j){
          const int col = colb + j*16 + fRow;
          const float bvx = b1[col];
#pragma unroll
          for (int r = 0; r < 4; ++r){
            const int row = mf*16 + kq*4 + r;
            const float v = gelu_f(acc[mf][j][r] + bvx);
            const unsigned off = ((unsigned)(row*N1 + col)*2u) ^ ((unsigned)(row & 7) << 4);
            *(bf16*)(smem + off) = __float2bfloat16(v);
          }
        }
      }
    } else if constexpr (NG > 0 && EPI == 2){
      const float b1v0 = b1[colb + fRow],       b1v1 = b1[colb + 16 + fRow];
      const float wg0  = Wg2[colb - N1 + fRow], wg1  = Wg2[colb - N1 + 16 + fRow];
#pragma unroll
      for (int mf = 0; mf < MF; ++mf){
#pragma unroll
        for (int r = 0; r < 4; ++r){
          float p = gelu_f(acc[mf][0][r] + b1v0) * wg0
                  + gelu_f(acc[mf][1][r] + b1v1) * wg1;
          p += __shfl_xor(p, 1); p += __shfl_xor(p, 2);
          p += __shfl_xor(p, 4); p += __shfl_xor(p, 8);
          if (fRow == 0) atomicAdd(&gate_lds[mf*16 + kq*4 + r], p);
        }
      }
    }
  }
  __syncthreads();   // H1 + gate partials complete, visible to all waves

  if constexpr (EPI == 2){
    if (t < BM) gate_lds[t] = 1.f / (1.f + __expf(-(gate_lds[t] + bg2p[0])));
  }

  // ---------------- phase B: C = H1 @ W2 + b2 ----------------
  const int colb2 = w * (N2 / 8);
  const bf16* cp0 = W2p + ((size_t)((colb2>>4)    ) * NKB) * 512 + lo8;
  const bf16* cp1 = W2p + ((size_t)((colb2>>4) + 1) * NKB) * 512 + lo8;

#pragma unroll
  for (int mf = 0; mf < MF; ++mf)
#pragma unroll
    for (int j = 0; j < 2; ++j)
#pragma unroll
      for (int r = 0; r < 4; ++r) acc[mf][j][r] = 0.f;

#pragma unroll
  for (int kt = 0; kt < NKB; ++kt){
    const bf16x8 c0 = *reinterpret_cast<const bf16x8*>(cp0 + kt*512);
    const bf16x8 c1 = *reinterpret_cast<const bf16x8*>(cp1 + kt*512);
#pragma unroll
    for (int mf = 0; mf < MF; ++mf){
      const int row = mf*16 + fRow;
      const unsigned off = ((unsigned)(row*N1 + kt*32 + kOff)*2u) ^ ((unsigned)(row & 7) << 4);
      const bf16x8 af = *reinterpret_cast<const bf16x8*>(smem + off);
      acc[mf][0] = __builtin_amdgcn_mfma_f32_16x16x32_bf16(af, c0, acc[mf][0], 0, 0, 0);
      acc[mf][1] = __builtin_amdgcn_mfma_f32_16x16x32_bf16(af, c1, acc[mf][1], 0, 0, 0);
    }
  }

  if constexpr (EPI == 2){
    // scatter epilogue: inc[(b*NN + slot[tok])*D + col] += (C + b2) * gate
    __syncthreads();                    // gate_lds sigmoid + all H1 reads done
    const int bb = bm0 >> 12;           // batch (BM divides 4096)
#pragma unroll
    for (int mf = 0; mf < MF; ++mf){
      float gr[4]; int sl[4];
#pragma unroll
      for (int r = 0; r < 4; ++r){
        const int row = mf*16 + kq*4 + r;
        gr[r] = gate_lds[row];
        sl[r] = slot_lds[row];
      }
#pragma unroll
      for (int j = 0; j < 2; ++j){
        const int col = colb2 + j*16 + fRow;
        const float bvx = b2[col];
#pragma unroll
        for (int r = 0; r < 4; ++r)
          atomicAdd(incp + ((size_t)(bb*NN + sl[r]))*D + col, (acc[mf][j][r] + bvx) * gr[r]);
      }
    }
  } else {
    // fused residual + LayerNorm (BM=32, rows complete across the 8 waves' cols)
    float vals[MF][2][4];
#pragma unroll
    for (int mf = 0; mf < MF; ++mf){
      const int row0 = mf*16 + kq*4;
#pragma unroll
      for (int j = 0; j < 2; ++j){
        const int col = colb2 + j*16 + fRow;
        const float bvx = b2[col];
#pragma unroll
        for (int r = 0; r < 4; ++r)
          vals[mf][j][r] = S[(size_t)(bm0 + row0 + r)*N2 + col] + acc[mf][j][r] + bvx;
      }
    }
    __syncthreads();                    // all H1 reads done; smem reusable
    float* red = (float*)smem;          // [BM rows][8 waves][2]
#pragma unroll
    for (int mf = 0; mf < MF; ++mf)
#pragma unroll
      for (int r = 0; r < 4; ++r){
        float s = 0.f, q = 0.f;
#pragma unroll
        for (int j = 0; j < 2; ++j){ s += vals[mf][j][r]; q += vals[mf][j][r]*vals[mf][j][r]; }
        s += __shfl_xor(s, 1); s += __shfl_xor(s, 2); s += __shfl_xor(s, 4); s += __shfl_xor(s, 8);
        q += __shfl_xor(q, 1); q += __shfl_xor(q, 2); q += __shfl_xor(q, 4); q += __shfl_xor(q, 8);
        if (fRow == 0){
          const int row = mf*16 + kq*4 + r;
          red[(row*8 + w)*2 + 0] = s;
          red[(row*8 + w)*2 + 1] = q;
        }
      }
    __syncthreads();
    float* mur = (float*)smem + BM*8*2;
    if (t < BM){
      float s = 0.f, q = 0.f;
      for (int w2 = 0; w2 < 8; w2++){ s += red[(t*8 + w2)*2]; q += red[(t*8 + w2)*2 + 1]; }
      const float mu = s * (1.f/256.f);
      const float var = q * (1.f/256.f) - mu*mu;
      mur[t*2] = mu; mur[t*2 + 1] = rsqrtf(var + 1e-5f);
    }
    __syncthreads();
#pragma unroll
    for (int mf = 0; mf < MF; ++mf){
      const int row0 = mf*16 + kq*4;
#pragma unroll
      for (int j = 0; j < 2; ++j){
        const int col = colb2 + j*16 + fRow;
        const float lw = lnw[col], lb = lnb[col];
#pragma unroll
        for (int r = 0; r < 4; ++r){
          const int row = row0 + r;
          ((float*)Cout)[(size_t)(bm0 + row)*N2 + col] =
              (vals[mf][j][r] - mur[row*2]) * mur[row*2 + 1] * lw + lb;
        }
      }
    }
  }
}

// fp32 routing GEMM (R13 config, restored)
__global__ __launch_bounds__(256) void route4_k(const float* __restrict__ X,
                                                const float* __restrict__ Wcat,
                                                int* __restrict__ slot_out)
{
  __shared__ float lds[128 * 84];
  float* Xs = lds;                      // [16][136]
  float* Ws = lds + 16 * 136;           // [16][80]
  float* Cs = lds;                      // [128][84] epilogue alias

  const int t = threadIdx.x;
  const int tok0 = blockIdx.x * 128;
  const int cq = t & 15;
  const int tg = t >> 4;
  const int stok = t >> 2, skq = t & 3;

  const float* xsrc0 = X + (size_t)(tok0 + stok) * D + 4*skq;
  const float* xsrc1 = X + (size_t)(tok0 + 64 + stok) * D + 4*skq;
  const int wrow0 = t / 20,        wc0 = t - wrow0*20;
  const int wrow1 = (256+t) / 20,  wc1 = (256+t) - wrow1*20;

  float accg[8][4] = {};
  float accs[8] = {};

  float4 xr0 = *reinterpret_cast<const float4*>(xsrc0);
  float4 xr1 = *reinterpret_cast<const float4*>(xsrc1);
  float4 wr0 = *reinterpret_cast<const float4*>(Wcat + (size_t)wrow0*80 + 4*wc0);
  float4 wr1;
  if (t < 64) wr1 = *reinterpret_cast<const float4*>(Wcat + (size_t)wrow1*80 + 4*wc1);

  for (int kt = 0; kt < 16; ++kt){
    __syncthreads();
    Xs[(4*skq+0)*136 + stok] = xr0.x;
    Xs[(4*skq+1)*136 + stok] = xr0.y;
    Xs[(4*skq+2)*136 + stok] = xr0.z;
    Xs[(4*skq+3)*136 + stok] = xr0.w;
    Xs[(4*skq+0)*136 + 64 + stok] = xr1.x;
    Xs[(4*skq+1)*136 + 64 + stok] = xr1.y;
    Xs[(4*skq+2)*136 + 64 + stok] = xr1.z;
    Xs[(4*skq+3)*136 + 64 + stok] = xr1.w;
    *reinterpret_cast<float4*>(&Ws[wrow0*80 + 4*wc0]) = wr0;
    if (t < 64) *reinterpret_cast<float4*>(&Ws[wrow1*80 + 4*wc1]) = wr1;
    __syncthreads();
    if (kt < 15){
      const int ko = (kt+1)*16;
      xr0 = *reinterpret_cast<const float4*>(xsrc0 + ko);
      xr1 = *reinterpret_cast<const float4*>(xsrc1 + ko);
      wr0 = *reinterpret_cast<const float4*>(Wcat + (size_t)(ko + wrow0)*80 + 4*wc0);
      if (t < 64) wr1 = *reinterpret_cast<const float4*>(Wcat + (size_t)(ko + wrow1)*80 + 4*wc1);
    }
#pragma unroll
    for (int k = 0; k < 16; ++k){
      const float4 xa = *reinterpret_cast<const float4*>(&Xs[k*136 + tg*8]);
      const float4 xb = *reinterpret_cast<const float4*>(&Xs[k*136 + tg*8 + 4]);
      const float4 wq = *reinterpret_cast<const float4*>(&Ws[k*80 + 4*cq]);
      const float wsv = Ws[k*80 + 64 + cq];
      const float xv[8] = {xa.x, xa.y, xa.z, xa.w, xb.x, xb.y, xb.z, xb.w};
#pragma unroll
      for (int m = 0; m < 8; m++){
        accg[m][0] = fmaf(xv[m], wq.x, accg[m][0]);
        accg[m][1] = fmaf(xv[m], wq.y, accg[m][1]);
        accg[m][2] = fmaf(xv[m], wq.z, accg[m][2]);
        accg[m][3] = fmaf(xv[m], wq.w, accg[m][3]);
        accs[m]    = fmaf(xv[m], wsv,  accs[m]);
      }
    }
  }

  __syncthreads();
#pragma unroll
  for (int m = 0; m < 8; m++){
    const int tok = tg*8 + m;
    Cs[tok*84 + 4*cq + 0] = accg[m][0];
    Cs[tok*84 + 4*cq + 1] = accg[m][1];
    Cs[tok*84 + 4*cq + 2] = accg[m][2];
    Cs[tok*84 + 4*cq + 3] = accg[m][3];
    Cs[tok*84 + 64 + cq]  = accs[m];
  }
  __syncthreads();
  if (t < 128){
    const float* row = &Cs[t * 84];
    float bg = row[0]; int big = 0;
    for (int g = 1; g < 64; ++g){ const float v = row[g]; if (v > bg){ bg = v; big = g; } }
    float bs = row[64]; int bis = 0;
    for (int s2 = 1; s2 < 16; ++s2){ const float v = row[64 + s2]; if (v > bs){ bs = v; bis = s2; } }
    slot_out[tok0 + t] = big * KK + bis;
  }
}

} // namespace

extern "C" void kernel_launch(void* const* d_in, const int* in_sizes, int n_in,
                              void* d_out, int out_size, void* d_ws, size_t ws_size,
                              hipStream_t stream)
{
  (void)in_sizes; (void)n_in; (void)out_size; (void)ws_size;
  const float* X   = (const float*)d_in[0];
  const float* S   = (const float*)d_in[1];
  const float* Wgr = (const float*)d_in[2];
  const float* Wsl = (const float*)d_in[3];
  const float* Wm1 = (const float*)d_in[4];
  const float* bm1 = (const float*)d_in[5];
  const float* Wm2 = (const float*)d_in[6];
  const float* bm2 = (const float*)d_in[7];
  const float* Wg1 = (const float*)d_in[8];
  const float* bg1 = (const float*)d_in[9];
  const float* Wg2 = (const float*)d_in[10];
  const float* bg2 = (const float*)d_in[11];
  const float* Wu1 = (const float*)d_in[12];
  const float* bu1 = (const float*)d_in[13];
  const float* Wu2 = (const float*)d_in[14];
  const float* bu2 = (const float*)d_in[15];
  const float* lnw = (const float*)d_in[16];
  const float* lnb = (const float*)d_in[17];
  float* out = (float*)d_out;

  char* ws = (char*)d_ws;
  bf16* Xp   = (bf16*)(ws + 0);                   // 16,777,216 B (packed X)
  bf16* Hp   = (bf16*)(ws + 16777216);            //  8,388,608 B (packed [S|inc])
  bf16* W1p  = (bf16*)(ws + 67108864);            // 393,216 B (packed [Wm1|Wg1], NK=8)
  bf16* W2p  = (bf16*)(ws + 67108864 + 393216);   // 262,144 B (packed Wm2, NK=16)
  bf16* Wu1p = (bf16*)(ws + 67108864 + 655360);   // 524,288 B (packed Wu1, NK=16)
  bf16* Wu2p = (bf16*)(ws + 67108864 + 1179648);  // 262,144 B (packed Wu2, NK=16)
  int*   slot = (int*)  (ws + 68550656);          // 131,072 B
  float* inc  = (float*)(ws + 68812800);          // 8,388,608 B
  float* Wcat = (float*)(ws + 77201408);          // 81,920 B
  float* bcat = (float*)(ws + 77201408 + 81920);  // 3,072 B

  prep_w_k<<<(742144 + 255)/256, 256, 0, stream>>>(Wm1, Wg1, Wm2, Wu1, Wu2, Wgr, Wsl, bm1, bg1,
                                                   W1p, W2p, Wu1p, Wu2p, Wcat, bcat);
  cvt_pack_x_k<<<4096, 256, 0, stream>>>(X, Xp);

  route4_k<<<NTOK/128, 256, 0, stream>>>(X, Wcat, slot);
  hipMemsetAsync(inc, 0, (size_t)NSLOT*D*sizeof(float), stream);

  // fused msg MLP + gate + scatter: inc[slot] += (gelu(X@Wm1+bm1)@Wm2+bm2) * sigmoid(gate)
  fused2_k<256, 512, 256, 256, 64, 2><<<NTOK/64, 512, 0, stream>>>(
      Xp, W1p, bcat, W2p, bm2, nullptr,
      nullptr, nullptr, nullptr, Wg2, slot, bg2, inc);

  // pack H = [S | inc] into fragment order for the update MLP
  pack_h_k<<<2048, 256, 0, stream>>>(S, inc, Hp);

  // fused slot-update MLP + residual + LayerNorm -> out
  fused2_k<512, 512, 0, 256, 32, 1><<<NSLOT/32, 512, 0, stream>>>(
      Hp, Wu1p, bu1, Wu2p, bu2, out,
      S, lnw, lnb, nullptr, nullptr, nullptr, nullptr);
}

// Round 18
// 144.403 us; speedup vs baseline: 1.2032x; 1.0421x over previous
//
#include <hip/hip_runtime.h>
#include <hip/hip_bf16.h>

using bf16 = __hip_bfloat16;
typedef __attribute__((ext_vector_type(8))) __bf16 bf16x8;
typedef __attribute__((ext_vector_type(4))) float f32x4;

namespace {

constexpr int D     = 256;
constexpr int NTOK  = 32768;   // B*L
constexpr int NSLOT = 8192;    // B*N
constexpr int GG    = 64;
constexpr int KK    = 16;
constexpr int NN    = 1024;

// Abramowitz–Stegun 7.1.26 rational erf, |err| <= 1.5e-7
__device__ __forceinline__ float erf_fast(float x){
  const float ax = fabsf(x);
  const float tt = 1.0f / fmaf(0.3275911f, ax, 1.0f);
  float p = fmaf(1.061405429f, tt, -1.453152027f);
  p = fmaf(p, tt, 1.421413741f);
  p = fmaf(p, tt, -0.284496736f);
  p = fmaf(p, tt, 0.254829592f);
  p *= tt;
  const float e = __expf(-ax*ax);
  const float r = 1.0f - p*e;
  return copysignf(r, x);
}

__device__ __forceinline__ float gelu_f(float x){
  return 0.5f * x * (1.0f + erf_fast(x * 0.70710678118654752f));
}

__device__ __forceinline__ void async_ld16(const void* g, void* l){
  typedef const __attribute__((address_space(1))) unsigned int gu32;
  typedef __attribute__((address_space(3))) unsigned int lu32;
  __builtin_amdgcn_global_load_lds((gu32*)g, (lu32*)l, 16, 0, 0);
}

struct alignas(16) ushort8s { unsigned short v[8]; };

__device__ __forceinline__ ushort8s pack8(const float* src){
  const float4 f0 = reinterpret_cast<const float4*>(src)[0];
  const float4 f1 = reinterpret_cast<const float4*>(src)[1];
  ushort8s u;
  u.v[0] = __bfloat16_as_ushort(__float2bfloat16(f0.x));
  u.v[1] = __bfloat16_as_ushort(__float2bfloat16(f0.y));
  u.v[2] = __bfloat16_as_ushort(__float2bfloat16(f0.z));
  u.v[3] = __bfloat16_as_ushort(__float2bfloat16(f0.w));
  u.v[4] = __bfloat16_as_ushort(__float2bfloat16(f1.x));
  u.v[5] = __bfloat16_as_ushort(__float2bfloat16(f1.y));
  u.v[6] = __bfloat16_as_ushort(__float2bfloat16(f1.z));
  u.v[7] = __bfloat16_as_ushort(__float2bfloat16(f1.w));
  return u;
}

// ---------------------------------------------------------------------------
// Fragment-packed layout: logical Wt[N][K] bf16 stored as 1KB tiles
//   flat = ((ng*NK + kt)*64 + fRow*4 + kq)*8 + e
// A wave's fragment load for (ng, kt) is ONE contiguous 1KB read. A block's
// whole A-tile (BM rows) is one contiguous BM*K*2-byte region -> LDS-stageable
// with linear global_load_lds.
// ---------------------------------------------------------------------------

__global__ void prep_w_k(const float* __restrict__ Wm1, const float* __restrict__ Wg1,
                         const float* __restrict__ Wm2, const float* __restrict__ Wu1,
                         const float* __restrict__ Wu2, const float* __restrict__ Wgr,
                         const float* __restrict__ Wsl, const float* __restrict__ bm1,
                         const float* __restrict__ bg1,
                         bf16* __restrict__ W1p, bf16* __restrict__ W2p,
                         bf16* __restrict__ Wu1p, bf16* __restrict__ Wu2p,
                         float* __restrict__ Wcat, float* __restrict__ bcat)
{
  const int idx = blockIdx.x*256 + threadIdx.x;
  if (idx < 196608){                                    // W1cat packed, NK=8
    const int e = idx&7, q = (idx>>3)&3, f = (idx>>5)&15, tile = idx>>9;
    const int kt = tile&7, ng = tile>>3;
    const int n = ng*16+f, k = kt*32+q*8+e;
    W1p[idx] = __float2bfloat16(n < 512 ? Wm1[k*512+n] : Wg1[k*256+(n-512)]);
  } else if (idx < 327680){                             // Wm2 packed, NK=16
    const int i = idx-196608;
    const int e = i&7, q = (i>>3)&3, f = (i>>5)&15, tile = i>>9;
    const int kt = tile&15, ng = tile>>4;
    W2p[i] = __float2bfloat16(Wm2[(kt*32+q*8+e)*256 + ng*16+f]);
  } else if (idx < 589824){                             // Wu1 packed, NK=16
    const int i = idx-327680;
    const int e = i&7, q = (i>>3)&3, f = (i>>5)&15, tile = i>>9;
    const int kt = tile&15, ng = tile>>4;
    Wu1p[i] = __float2bfloat16(Wu1[(kt*32+q*8+e)*512 + ng*16+f]);
  } else if (idx < 720896){                             // Wu2 packed, NK=16
    const int i = idx-589824;
    const int e = i&7, q = (i>>3)&3, f = (i>>5)&15, tile = i>>9;
    const int kt = tile&15, ng = tile>>4;
    Wu2p[i] = __float2bfloat16(Wu2[(kt*32+q*8+e)*256 + ng*16+f]);
  } else if (idx < 741376){                             // Wcat [256][80] fp32 (k-major)
    const int i = idx - 720896, k = i / 80, c = i - k*80;
    Wcat[i] = (c < GG) ? Wgr[k*GG + c] : Wsl[k*KK + (c - GG)];
  } else if (idx < 742144){                             // bcat [768]
    const int c = idx - 741376;
    bcat[c] = (c < 512) ? bm1[c] : bg1[c - 512];
  }
}

// H = [S | inc] (8192x512 f32 logical) -> packed bf16, NK=16.
__global__ void pack_h_k(const float* __restrict__ S, const float* __restrict__ inc,
                         bf16* __restrict__ Hp){
  const int chunk = blockIdx.x*256 + threadIdx.x;       // over 524288
  const int q = chunk&3, f = (chunk>>2)&15, tile = chunk>>6;
  const int kt = tile&15, ng = tile>>4;
  const int r = ng*16+f, c = kt*32+q*8;
  const float* src = (c < 256) ? (S + (size_t)r*256 + c) : (inc + (size_t)r*256 + (c-256));
  reinterpret_cast<ushort8s*>(Hp)[chunk] = pack8(src);
}

// ---------------------------------------------------------------------------
// Fused 2-layer MLP, fragment-packed operands, A-tile staged in LDS.
// (unchanged from R16 — msg declared structurally latency-bound)
// ---------------------------------------------------------------------------
template<int K, int N1, int NG, int N2, int BM, int EPI>
__global__ __launch_bounds__(512, 1) void fused2_k(
    const bf16* __restrict__ Ap,
    const bf16* __restrict__ W1p, const float* __restrict__ b1,
    const bf16* __restrict__ W2p, const float* __restrict__ b2,
    void* __restrict__ Cout,
    const float* __restrict__ S, const float* __restrict__ lnw, const float* __restrict__ lnb,
    const float* __restrict__ Wg2,
    const int* __restrict__ slotp, const float* __restrict__ bg2p, float* __restrict__ incp)
{
  constexpr int SLICE = (N1 + NG) / 8;  // cols per wave, phase A (96 or 64)
  constexpr int SP    = SLICE / 32;     // 32-col sub-phases
  constexpr int MF    = BM / 16;        // M fragments (4 or 2)
  constexpr int NKA   = K / 32;
  constexpr int NKB   = N1 / 32;
  constexpr int H1B   = BM * N1 * 2;    // LDS bytes for H1
  constexpr int AB    = BM * K * 2;     // LDS bytes for A tile (32KB both kernels)
  __shared__ alignas(16) char smem[H1B];
  __shared__ alignas(16) char As_lds[AB];
  __shared__ float gate_lds[EPI == 2 ? BM : 1];
  __shared__ int   slot_lds[EPI == 2 ? BM : 1];

  const int t = threadIdx.x, lane = t & 63, w = t >> 6;
  const int fRow = lane & 15, kq = lane >> 4, kOff = kq * 8;
  const int lo8 = (fRow*4 + kq) * 8;    // per-lane elem offset within a 1KB tile
  const int bm0 = blockIdx.x * BM;

  // ---- stage A tile: contiguous region in packed layout, linear LDS dest ----
  {
    const bf16* Asrc = Ap + (size_t)(bm0 >> 4) * NKA * 512;
#pragma unroll
    for (int u = t; u < AB/16; u += 512)
      async_ld16(Asrc + u*8, (bf16*)As_lds + u*8);
  }
  if constexpr (EPI == 2){
    if (t < BM){ gate_lds[t] = 0.f; slot_lds[t] = slotp[bm0 + t]; }
  }
  asm volatile("s_waitcnt vmcnt(0)" ::: "memory");
  __syncthreads();

  f32x4 acc[MF][2];                     // single accumulator, reused by phase B

  // ---------------- phase A ----------------
  for (int sp = 0; sp < SP; ++sp){
    const int colb = w * SLICE + sp * 32;
    const bf16* bp0 = W1p + ((size_t)((colb>>4)    ) * NKA) * 512 + lo8;
    const bf16* bp1 = W1p + ((size_t)((colb>>4) + 1) * NKA) * 512 + lo8;

#pragma unroll
    for (int mf = 0; mf < MF; ++mf)
#pragma unroll
      for (int j = 0; j < 2; ++j)
#pragma unroll
        for (int r = 0; r < 4; ++r) acc[mf][j][r] = 0.f;

#pragma unroll
    for (int kt = 0; kt < NKA; ++kt){
      const bf16x8 b0  = *reinterpret_cast<const bf16x8*>(bp0 + kt*512);
      const bf16x8 b1v = *reinterpret_cast<const bf16x8*>(bp1 + kt*512);
#pragma unroll
      for (int mf = 0; mf < MF; ++mf){
        const bf16x8 a = *reinterpret_cast<const bf16x8*>(
            (const bf16*)As_lds + ((mf*NKA + kt)*512 + lo8));
        acc[mf][0] = __builtin_amdgcn_mfma_f32_16x16x32_bf16(a, b0,  acc[mf][0], 0, 0, 0);
        acc[mf][1] = __builtin_amdgcn_mfma_f32_16x16x32_bf16(a, b1v, acc[mf][1], 0, 0, 0);
      }
    }

    // sub-phase epilogue: H1 write (swizzled) or gate accumulation into LDS
    if (NG == 0 || colb < N1){
#pragma unroll
      for (int mf = 0; mf < MF; ++mf){
#pragma unroll
        for (int j = 0; j < 2; ++j){
          const int col = colb + j*16 + fRow;
          const float bvx = b1[col];
#pragma unroll
          for (int r = 0; r < 4; ++r){
            const int row = mf*16 + kq*4 + r;
            const float v = gelu_f(acc[mf][j][r] + bvx);
            const unsigned off = ((unsigned)(row*N1 + col)*2u) ^ ((unsigned)(row & 7) << 4);
            *(bf16*)(smem + off) = __float2bfloat16(v);
          }
        }
      }
    } else if constexpr (NG > 0 && EPI == 2){
      const float b1v0 = b1[colb + fRow],       b1v1 = b1[colb + 16 + fRow];
      const float wg0  = Wg2[colb - N1 + fRow], wg1  = Wg2[colb - N1 + 16 + fRow];
#pragma unroll
      for (int mf = 0; mf < MF; ++mf){
#pragma unroll
        for (int r = 0; r < 4; ++r){
          float p = gelu_f(acc[mf][0][r] + b1v0) * wg0
                  + gelu_f(acc[mf][1][r] + b1v1) * wg1;
          p += __shfl_xor(p, 1); p += __shfl_xor(p, 2);
          p += __shfl_xor(p, 4); p += __shfl_xor(p, 8);
          if (fRow == 0) atomicAdd(&gate_lds[mf*16 + kq*4 + r], p);
        }
      }
    }
  }
  __syncthreads();   // H1 + gate partials complete, visible to all waves

  if constexpr (EPI == 2){
    if (t < BM) gate_lds[t] = 1.f / (1.f + __expf(-(gate_lds[t] + bg2p[0])));
  }

  // ---------------- phase B: C = H1 @ W2 + b2 ----------------
  const int colb2 = w * (N2 / 8);
  const bf16* cp0 = W2p + ((size_t)((colb2>>4)    ) * NKB) * 512 + lo8;
  const bf16* cp1 = W2p + ((size_t)((colb2>>4) + 1) * NKB) * 512 + lo8;

#pragma unroll
  for (int mf = 0; mf < MF; ++mf)
#pragma unroll
    for (int j = 0; j < 2; ++j)
#pragma unroll
      for (int r = 0; r < 4; ++r) acc[mf][j][r] = 0.f;

#pragma unroll
  for (int kt = 0; kt < NKB; ++kt){
    const bf16x8 c0 = *reinterpret_cast<const bf16x8*>(cp0 + kt*512);
    const bf16x8 c1 = *reinterpret_cast<const bf16x8*>(cp1 + kt*512);
#pragma unroll
    for (int mf = 0; mf < MF; ++mf){
      const int row = mf*16 + fRow;
      const unsigned off = ((unsigned)(row*N1 + kt*32 + kOff)*2u) ^ ((unsigned)(row & 7) << 4);
      const bf16x8 af = *reinterpret_cast<const bf16x8*>(smem + off);
      acc[mf][0] = __builtin_amdgcn_mfma_f32_16x16x32_bf16(af, c0, acc[mf][0], 0, 0, 0);
      acc[mf][1] = __builtin_amdgcn_mfma_f32_16x16x32_bf16(af, c1, acc[mf][1], 0, 0, 0);
    }
  }

  if constexpr (EPI == 2){
    // scatter epilogue: inc[(b*NN + slot[tok])*D + col] += (C + b2) * gate
    __syncthreads();                    // gate_lds sigmoid + all H1 reads done
    const int bb = bm0 >> 12;           // batch (BM divides 4096)
#pragma unroll
    for (int mf = 0; mf < MF; ++mf){
      float gr[4]; int sl[4];
#pragma unroll
      for (int r = 0; r < 4; ++r){
        const int row = mf*16 + kq*4 + r;
        gr[r] = gate_lds[row];
        sl[r] = slot_lds[row];
      }
#pragma unroll
      for (int j = 0; j < 2; ++j){
        const int col = colb2 + j*16 + fRow;
        const float bvx = b2[col];
#pragma unroll
        for (int r = 0; r < 4; ++r)
          atomicAdd(incp + ((size_t)(bb*NN + sl[r]))*D + col, (acc[mf][j][r] + bvx) * gr[r]);
      }
    }
  } else {
    // fused residual + LayerNorm (BM=32, rows complete across the 8 waves' cols)
    float vals[MF][2][4];
#pragma unroll
    for (int mf = 0; mf < MF; ++mf){
      const int row0 = mf*16 + kq*4;
#pragma unroll
      for (int j = 0; j < 2; ++j){
        const int col = colb2 + j*16 + fRow;
        const float bvx = b2[col];
#pragma unroll
        for (int r = 0; r < 4; ++r)
          vals[mf][j][r] = S[(size_t)(bm0 + row0 + r)*N2 + col] + acc[mf][j][r] + bvx;
      }
    }
    __syncthreads();                    // all H1 reads done; smem reusable
    float* red = (float*)smem;          // [BM rows][8 waves][2]
#pragma unroll
    for (int mf = 0; mf < MF; ++mf)
#pragma unroll
      for (int r = 0; r < 4; ++r){
        float s = 0.f, q = 0.f;
#pragma unroll
        for (int j = 0; j < 2; ++j){ s += vals[mf][j][r]; q += vals[mf][j][r]*vals[mf][j][r]; }
        s += __shfl_xor(s, 1); s += __shfl_xor(s, 2); s += __shfl_xor(s, 4); s += __shfl_xor(s, 8);
        q += __shfl_xor(q, 1); q += __shfl_xor(q, 2); q += __shfl_xor(q, 4); q += __shfl_xor(q, 8);
        if (fRow == 0){
          const int row = mf*16 + kq*4 + r;
          red[(row*8 + w)*2 + 0] = s;
          red[(row*8 + w)*2 + 1] = q;
        }
      }
    __syncthreads();
    float* mur = (float*)smem + BM*8*2;
    if (t < BM){
      float s = 0.f, q = 0.f;
      for (int w2 = 0; w2 < 8; w2++){ s += red[(t*8 + w2)*2]; q += red[(t*8 + w2)*2 + 1]; }
      const float mu = s * (1.f/256.f);
      const float var = q * (1.f/256.f) - mu*mu;
      mur[t*2] = mu; mur[t*2 + 1] = rsqrtf(var + 1e-5f);
    }
    __syncthreads();
#pragma unroll
    for (int mf = 0; mf < MF; ++mf){
      const int row0 = mf*16 + kq*4;
#pragma unroll
      for (int j = 0; j < 2; ++j){
        const int col = colb2 + j*16 + fRow;
        const float lw = lnw[col], lb = lnb[col];
#pragma unroll
        for (int r = 0; r < 4; ++r){
          const int row = row0 + r;
          ((float*)Cout)[(size_t)(bm0 + row)*N2 + col] =
              (vals[mf][j][r] - mur[row*2]) * mur[row*2 + 1] * lw + lb;
        }
      }
    }
  }
}

// fp32 routing GEMM + fused X bf16-packing (route reads every X element once;
// emit the fragment-packed Xp as a side-effect -> deletes cvt_pack_x_k).
__global__ __launch_bounds__(256) void route5_k(const float* __restrict__ X,
                                                const float* __restrict__ Wcat,
                                                int* __restrict__ slot_out,
                                                bf16* __restrict__ Xp)
{
  __shared__ float lds[128 * 84];
  float* Xs = lds;                      // [16][136]
  float* Ws = lds + 16 * 136;           // [16][80]
  float* Cs = lds;                      // [128][84] epilogue alias

  const int t = threadIdx.x;
  const int tok0 = blockIdx.x * 128;
  const int cq = t & 15;
  const int tg = t >> 4;
  const int stok = t >> 2, skq = t & 3;

  const float* xsrc0 = X + (size_t)(tok0 + stok) * D + 4*skq;
  const float* xsrc1 = X + (size_t)(tok0 + 64 + stok) * D + 4*skq;
  const int wrow0 = t / 20,        wc0 = t - wrow0*20;
  const int wrow1 = (256+t) / 20,  wc1 = (256+t) - wrow1*20;

  float accg[8][4] = {};
  float accs[8] = {};

  // packed-X write: (tok, k0..k0+3) -> Xp[((ng*8+kt)*64 + f*4+q)*8 + e0 ..]
  auto packw = [&](int tok, int k0, float4 v){
    const int ng = tok >> 4, f = tok & 15;
    const int kt = k0 >> 5, q = (k0 >> 3) & 3, e0 = k0 & 7;
    const size_t off = ((size_t)(ng*8 + kt)*64 + (f*4 + q))*8 + e0;
    ushort4 u;
    u.x = __bfloat16_as_ushort(__float2bfloat16(v.x));
    u.y = __bfloat16_as_ushort(__float2bfloat16(v.y));
    u.z = __bfloat16_as_ushort(__float2bfloat16(v.z));
    u.w = __bfloat16_as_ushort(__float2bfloat16(v.w));
    *reinterpret_cast<ushort4*>(Xp + off) = u;
  };

  float4 xr0 = *reinterpret_cast<const float4*>(xsrc0);
  float4 xr1 = *reinterpret_cast<const float4*>(xsrc1);
  float4 wr0 = *reinterpret_cast<const float4*>(Wcat + (size_t)wrow0*80 + 4*wc0);
  float4 wr1;
  if (t < 64) wr1 = *reinterpret_cast<const float4*>(Wcat + (size_t)wrow1*80 + 4*wc1);

  for (int kt = 0; kt < 16; ++kt){
    __syncthreads();
    Xs[(4*skq+0)*136 + stok] = xr0.x;
    Xs[(4*skq+1)*136 + stok] = xr0.y;
    Xs[(4*skq+2)*136 + stok] = xr0.z;
    Xs[(4*skq+3)*136 + stok] = xr0.w;
    Xs[(4*skq+0)*136 + 64 + stok] = xr1.x;
    Xs[(4*skq+1)*136 + 64 + stok] = xr1.y;
    Xs[(4*skq+2)*136 + 64 + stok] = xr1.z;
    Xs[(4*skq+3)*136 + 64 + stok] = xr1.w;
    *reinterpret_cast<float4*>(&Ws[wrow0*80 + 4*wc0]) = wr0;
    if (t < 64) *reinterpret_cast<float4*>(&Ws[wrow1*80 + 4*wc1]) = wr1;
    // fused bf16 pack of this iteration's X data (each element exactly once)
    packw(tok0 + stok,      kt*16 + 4*skq, xr0);
    packw(tok0 + 64 + stok, kt*16 + 4*skq, xr1);
    __syncthreads();
    if (kt < 15){
      const int ko = (kt+1)*16;
      xr0 = *reinterpret_cast<const float4*>(xsrc0 + ko);
      xr1 = *reinterpret_cast<const float4*>(xsrc1 + ko);
      wr0 = *reinterpret_cast<const float4*>(Wcat + (size_t)(ko + wrow0)*80 + 4*wc0);
      if (t < 64) wr1 = *reinterpret_cast<const float4*>(Wcat + (size_t)(ko + wrow1)*80 + 4*wc1);
    }
#pragma unroll
    for (int k = 0; k < 16; ++k){
      const float4 xa = *reinterpret_cast<const float4*>(&Xs[k*136 + tg*8]);
      const float4 xb = *reinterpret_cast<const float4*>(&Xs[k*136 + tg*8 + 4]);
      const float4 wq = *reinterpret_cast<const float4*>(&Ws[k*80 + 4*cq]);
      const float wsv = Ws[k*80 + 64 + cq];
      const float xv[8] = {xa.x, xa.y, xa.z, xa.w, xb.x, xb.y, xb.z, xb.w};
#pragma unroll
      for (int m = 0; m < 8; m++){
        accg[m][0] = fmaf(xv[m], wq.x, accg[m][0]);
        accg[m][1] = fmaf(xv[m], wq.y, accg[m][1]);
        accg[m][2] = fmaf(xv[m], wq.z, accg[m][2]);
        accg[m][3] = fmaf(xv[m], wq.w, accg[m][3]);
        accs[m]    = fmaf(xv[m], wsv,  accs[m]);
      }
    }
  }

  __syncthreads();
#pragma unroll
  for (int m = 0; m < 8; m++){
    const int tok = tg*8 + m;
    Cs[tok*84 + 4*cq + 0] = accg[m][0];
    Cs[tok*84 + 4*cq + 1] = accg[m][1];
    Cs[tok*84 + 4*cq + 2] = accg[m][2];
    Cs[tok*84 + 4*cq + 3] = accg[m][3];
    Cs[tok*84 + 64 + cq]  = accs[m];
  }
  __syncthreads();
  if (t < 128){
    const float* row = &Cs[t * 84];
    float bg = row[0]; int big = 0;
    for (int g = 1; g < 64; ++g){ const float v = row[g]; if (v > bg){ bg = v; big = g; } }
    float bs = row[64]; int bis = 0;
    for (int s2 = 1; s2 < 16; ++s2){ const float v = row[64 + s2]; if (v > bs){ bs = v; bis = s2; } }
    slot_out[tok0 + t] = big * KK + bis;
  }
}

} // namespace

extern "C" void kernel_launch(void* const* d_in, const int* in_sizes, int n_in,
                              void* d_out, int out_size, void* d_ws, size_t ws_size,
                              hipStream_t stream)
{
  (void)in_sizes; (void)n_in; (void)out_size; (void)ws_size;
  const float* X   = (const float*)d_in[0];
  const float* S   = (const float*)d_in[1];
  const float* Wgr = (const float*)d_in[2];
  const float* Wsl = (const float*)d_in[3];
  const float* Wm1 = (const float*)d_in[4];
  const float* bm1 = (const float*)d_in[5];
  const float* Wm2 = (const float*)d_in[6];
  const float* bm2 = (const float*)d_in[7];
  const float* Wg1 = (const float*)d_in[8];
  const float* bg1 = (const float*)d_in[9];
  const float* Wg2 = (const float*)d_in[10];
  const float* bg2 = (const float*)d_in[11];
  const float* Wu1 = (const float*)d_in[12];
  const float* bu1 = (const float*)d_in[13];
  const float* Wu2 = (const float*)d_in[14];
  const float* bu2 = (const float*)d_in[15];
  const float* lnw = (const float*)d_in[16];
  const float* lnb = (const float*)d_in[17];
  float* out = (float*)d_out;

  char* ws = (char*)d_ws;
  bf16* Xp   = (bf16*)(ws + 0);                   // 16,777,216 B (packed X)
  bf16* Hp   = (bf16*)(ws + 16777216);            //  8,388,608 B (packed [S|inc])
  bf16* W1p  = (bf16*)(ws + 67108864);            // 393,216 B (packed [Wm1|Wg1], NK=8)
  bf16* W2p  = (bf16*)(ws + 67108864 + 393216);   // 262,144 B (packed Wm2, NK=16)
  bf16* Wu1p = (bf16*)(ws + 67108864 + 655360);   // 524,288 B (packed Wu1, NK=16)
  bf16* Wu2p = (bf16*)(ws + 67108864 + 1179648);  // 262,144 B (packed Wu2, NK=16)
  int*   slot = (int*)  (ws + 68550656);          // 131,072 B
  float* inc  = (float*)(ws + 68812800);          // 8,388,608 B
  float* Wcat = (float*)(ws + 77201408);          // 81,920 B
  float* bcat = (float*)(ws + 77201408 + 81920);  // 3,072 B

  prep_w_k<<<(742144 + 255)/256, 256, 0, stream>>>(Wm1, Wg1, Wm2, Wu1, Wu2, Wgr, Wsl, bm1, bg1,
                                                   W1p, W2p, Wu1p, Wu2p, Wcat, bcat);

  // routing + fused X bf16 packing (replaces route4_k + cvt_pack_x_k)
  route5_k<<<NTOK/128, 256, 0, stream>>>(X, Wcat, slot, Xp);
  hipMemsetAsync(inc, 0, (size_t)NSLOT*D*sizeof(float), stream);

  // fused msg MLP + gate + scatter: inc[slot] += (gelu(X@Wm1+bm1)@Wm2+bm2) * sigmoid(gate)
  fused2_k<256, 512, 256, 256, 64, 2><<<NTOK/64, 512, 0, stream>>>(
      Xp, W1p, bcat, W2p, bm2, nullptr,
      nullptr, nullptr, nullptr, Wg2, slot, bg2, inc);

  // pack H = [S | inc] into fragment order for the update MLP
  pack_h_k<<<2048, 256, 0, stream>>>(S, inc, Hp);

  // fused slot-update MLP + residual + LayerNorm -> out
  fused2_k<512, 512, 0, 256, 32, 1><<<NSLOT/32, 512, 0, stream>>>(
      Hp, Wu1p, bu1, Wu2p, bu2, out,
      S, lnw, lnb, nullptr, nullptr, nullptr, nullptr);
}

// Round 19
// 141.144 us; speedup vs baseline: 1.2310x; 1.0231x over previous
//
#include <hip/hip_runtime.h>
#include <hip/hip_bf16.h>

using bf16 = __hip_bfloat16;
typedef __attribute__((ext_vector_type(8))) __bf16 bf16x8;
typedef __attribute__((ext_vector_type(4))) float f32x4;

namespace {

constexpr int D     = 256;
constexpr int NTOK  = 32768;   // B*L
constexpr int NSLOT = 8192;    // B*N
constexpr int GG    = 64;
constexpr int KK    = 16;
constexpr int NN    = 1024;

// Abramowitz–Stegun 7.1.26 rational erf, |err| <= 1.5e-7
__device__ __forceinline__ float erf_fast(float x){
  const float ax = fabsf(x);
  const float tt = 1.0f / fmaf(0.3275911f, ax, 1.0f);
  float p = fmaf(1.061405429f, tt, -1.453152027f);
  p = fmaf(p, tt, 1.421413741f);
  p = fmaf(p, tt, -0.284496736f);
  p = fmaf(p, tt, 0.254829592f);
  p *= tt;
  const float e = __expf(-ax*ax);
  const float r = 1.0f - p*e;
  return copysignf(r, x);
}

__device__ __forceinline__ float gelu_f(float x){
  return 0.5f * x * (1.0f + erf_fast(x * 0.70710678118654752f));
}

__device__ __forceinline__ void async_ld16(const void* g, void* l){
  typedef const __attribute__((address_space(1))) unsigned int gu32;
  typedef __attribute__((address_space(3))) unsigned int lu32;
  __builtin_amdgcn_global_load_lds((gu32*)g, (lu32*)l, 16, 0, 0);
}

struct alignas(16) ushort8s { unsigned short v[8]; };

__device__ __forceinline__ ushort8s pack8(const float* src){
  const float4 f0 = reinterpret_cast<const float4*>(src)[0];
  const float4 f1 = reinterpret_cast<const float4*>(src)[1];
  ushort8s u;
  u.v[0] = __bfloat16_as_ushort(__float2bfloat16(f0.x));
  u.v[1] = __bfloat16_as_ushort(__float2bfloat16(f0.y));
  u.v[2] = __bfloat16_as_ushort(__float2bfloat16(f0.z));
  u.v[3] = __bfloat16_as_ushort(__float2bfloat16(f0.w));
  u.v[4] = __bfloat16_as_ushort(__float2bfloat16(f1.x));
  u.v[5] = __bfloat16_as_ushort(__float2bfloat16(f1.y));
  u.v[6] = __bfloat16_as_ushort(__float2bfloat16(f1.z));
  u.v[7] = __bfloat16_as_ushort(__float2bfloat16(f1.w));
  return u;
}

// ---------------------------------------------------------------------------
// Fragment-packed layout: logical Wt[N][K] bf16 stored as 1KB tiles
//   flat = ((ng*NK + kt)*64 + fRow*4 + kq)*8 + e
// A wave's fragment load for (ng, kt) is ONE contiguous 1KB read. A block's
// whole A-tile (BM rows) is one contiguous BM*K*2-byte region.
// ---------------------------------------------------------------------------

__global__ void prep_w_k(const float* __restrict__ Wm1, const float* __restrict__ Wg1,
                         const float* __restrict__ Wm2, const float* __restrict__ Wu1,
                         const float* __restrict__ Wu2, const float* __restrict__ Wgr,
                         const float* __restrict__ Wsl, const float* __restrict__ bm1,
                         const float* __restrict__ bg1,
                         bf16* __restrict__ W1p, bf16* __restrict__ W2p,
                         bf16* __restrict__ Wu1p, bf16* __restrict__ Wu2p,
                         float* __restrict__ Wcat, float* __restrict__ bcat)
{
  const int idx = blockIdx.x*256 + threadIdx.x;
  if (idx < 196608){                                    // W1cat packed, NK=8
    const int e = idx&7, q = (idx>>3)&3, f = (idx>>5)&15, tile = idx>>9;
    const int kt = tile&7, ng = tile>>3;
    const int n = ng*16+f, k = kt*32+q*8+e;
    W1p[idx] = __float2bfloat16(n < 512 ? Wm1[k*512+n] : Wg1[k*256+(n-512)]);
  } else if (idx < 327680){                             // Wm2 packed, NK=16
    const int i = idx-196608;
    const int e = i&7, q = (i>>3)&3, f = (i>>5)&15, tile = i>>9;
    const int kt = tile&15, ng = tile>>4;
    W2p[i] = __float2bfloat16(Wm2[(kt*32+q*8+e)*256 + ng*16+f]);
  } else if (idx < 589824){                             // Wu1 packed, NK=16
    const int i = idx-327680;
    const int e = i&7, q = (i>>3)&3, f = (i>>5)&15, tile = i>>9;
    const int kt = tile&15, ng = tile>>4;
    Wu1p[i] = __float2bfloat16(Wu1[(kt*32+q*8+e)*512 + ng*16+f]);
  } else if (idx < 720896){                             // Wu2 packed, NK=16
    const int i = idx-589824;
    const int e = i&7, q = (i>>3)&3, f = (i>>5)&15, tile = i>>9;
    const int kt = tile&15, ng = tile>>4;
    Wu2p[i] = __float2bfloat16(Wu2[(kt*32+q*8+e)*256 + ng*16+f]);
  } else if (idx < 741376){                             // Wcat [256][80] fp32 (k-major)
    const int i = idx - 720896, k = i / 80, c = i - k*80;
    Wcat[i] = (c < GG) ? Wgr[k*GG + c] : Wsl[k*KK + (c - GG)];
  } else if (idx < 742144){                             // bcat [768]
    const int c = idx - 741376;
    bcat[c] = (c < 512) ? bm1[c] : bg1[c - 512];
  }
}

// ---------------------------------------------------------------------------
// Fused 2-layer MLP, fragment-packed operands, A-tile staged in LDS.
// AF32=0: A staged from packed bf16 Ap via global_load_lds (msg).
// AF32=1: A staged by reg-path from f32 [S | incp] with in-register bf16
//         convert (upd; replaces the pack_h kernel + Hp round-trip; byte-
//         identical LDS contents).
// EPI=1: C + S residual + LayerNorm -> f32 Cout (slot update).
// EPI=2: scatter epilogue — gate = sigmoid(gate_lds+bg2); atomicAdd
//        (C)*gate into inc[slot] directly.
// ---------------------------------------------------------------------------
template<int K, int N1, int NG, int N2, int BM, int EPI, int AF32>
__global__ __launch_bounds__(512, 1) void fused2_k(
    const bf16* __restrict__ Ap,
    const bf16* __restrict__ W1p, const float* __restrict__ b1,
    const bf16* __restrict__ W2p, const float* __restrict__ b2,
    void* __restrict__ Cout,
    const float* __restrict__ S, const float* __restrict__ lnw, const float* __restrict__ lnb,
    const float* __restrict__ Wg2,
    const int* __restrict__ slotp, const float* __restrict__ bg2p, float* __restrict__ incp)
{
  constexpr int SLICE = (N1 + NG) / 8;  // cols per wave, phase A (96 or 64)
  constexpr int SP    = SLICE / 32;     // 32-col sub-phases
  constexpr int MF    = BM / 16;        // M fragments (4 or 2)
  constexpr int NKA   = K / 32;
  constexpr int NKB   = N1 / 32;
  constexpr int H1B   = BM * N1 * 2;    // LDS bytes for H1
  constexpr int AB    = BM * K * 2;     // LDS bytes for A tile (32KB both kernels)
  __shared__ alignas(16) char smem[H1B];
  __shared__ alignas(16) char As_lds[AB];
  __shared__ float gate_lds[EPI == 2 ? BM : 1];
  __shared__ int   slot_lds[EPI == 2 ? BM : 1];

  const int t = threadIdx.x, lane = t & 63, w = t >> 6;
  const int fRow = lane & 15, kq = lane >> 4, kOff = kq * 8;
  const int lo8 = (fRow*4 + kq) * 8;    // per-lane elem offset within a 1KB tile
  const int bm0 = blockIdx.x * BM;

  // ---- stage A tile ----
  if constexpr (AF32 == 0){
    const bf16* Asrc = Ap + (size_t)(bm0 >> 4) * NKA * 512;
#pragma unroll
    for (int u = t; u < AB/16; u += 512)
      async_ld16(Asrc + u*8, (bf16*)As_lds + u*8);
    if constexpr (EPI == 2){
      if (t < BM){ gate_lds[t] = 0.f; slot_lds[t] = slotp[bm0 + t]; }
    }
    asm volatile("s_waitcnt vmcnt(0)" ::: "memory");
    __syncthreads();
  } else {
    // reg-path: [S | incp] f32 -> bf16 packed chunks (pack_h math, per block)
#pragma unroll
    for (int u = t; u < AB/16; u += 512){
      const int q = u & 3, f = (u >> 2) & 15, kt = (u >> 6) % NKA, ngl = u / (64*NKA);
      const int r = bm0 + ngl*16 + f, c = kt*32 + q*8;
      const float* src = (c < 256) ? (S + (size_t)r*256 + c)
                                   : (incp + (size_t)r*256 + (c - 256));
      reinterpret_cast<ushort8s*>(As_lds)[u] = pack8(src);
    }
    __syncthreads();
  }

  f32x4 acc[MF][2];                     // single accumulator, reused by phase B

  // ---------------- phase A ----------------
  for (int sp = 0; sp < SP; ++sp){
    const int colb = w * SLICE + sp * 32;
    const bf16* bp0 = W1p + ((size_t)((colb>>4)    ) * NKA) * 512 + lo8;
    const bf16* bp1 = W1p + ((size_t)((colb>>4) + 1) * NKA) * 512 + lo8;

#pragma unroll
    for (int mf = 0; mf < MF; ++mf)
#pragma unroll
      for (int j = 0; j < 2; ++j)
#pragma unroll
        for (int r = 0; r < 4; ++r) acc[mf][j][r] = 0.f;

#pragma unroll
    for (int kt = 0; kt < NKA; ++kt){
      const bf16x8 b0  = *reinterpret_cast<const bf16x8*>(bp0 + kt*512);
      const bf16x8 b1v = *reinterpret_cast<const bf16x8*>(bp1 + kt*512);
#pragma unroll
      for (int mf = 0; mf < MF; ++mf){
        const bf16x8 a = *reinterpret_cast<const bf16x8*>(
            (const bf16*)As_lds + ((mf*NKA + kt)*512 + lo8));
        acc[mf][0] = __builtin_amdgcn_mfma_f32_16x16x32_bf16(a, b0,  acc[mf][0], 0, 0, 0);
        acc[mf][1] = __builtin_amdgcn_mfma_f32_16x16x32_bf16(a, b1v, acc[mf][1], 0, 0, 0);
      }
    }

    // sub-phase epilogue: H1 write (swizzled) or gate accumulation into LDS
    if (NG == 0 || colb < N1){
#pragma unroll
      for (int mf = 0; mf < MF; ++mf){
#pragma unroll
        for (int j = 0; j < 2; ++j){
          const int col = colb + j*16 + fRow;
          const float bvx = b1[col];
#pragma unroll
          for (int r = 0; r < 4; ++r){
            const int row = mf*16 + kq*4 + r;
            const float v = gelu_f(acc[mf][j][r] + bvx);
            const unsigned off = ((unsigned)(row*N1 + col)*2u) ^ ((unsigned)(row & 7) << 4);
            *(bf16*)(smem + off) = __float2bfloat16(v);
          }
        }
      }
    } else if constexpr (NG > 0 && EPI == 2){
      const float b1v0 = b1[colb + fRow],       b1v1 = b1[colb + 16 + fRow];
      const float wg0  = Wg2[colb - N1 + fRow], wg1  = Wg2[colb - N1 + 16 + fRow];
#pragma unroll
      for (int mf = 0; mf < MF; ++mf){
#pragma unroll
        for (int r = 0; r < 4; ++r){
          float p = gelu_f(acc[mf][0][r] + b1v0) * wg0
                  + gelu_f(acc[mf][1][r] + b1v1) * wg1;
          p += __shfl_xor(p, 1); p += __shfl_xor(p, 2);
          p += __shfl_xor(p, 4); p += __shfl_xor(p, 8);
          if (fRow == 0) atomicAdd(&gate_lds[mf*16 + kq*4 + r], p);
        }
      }
    }
  }
  __syncthreads();   // H1 + gate partials complete, visible to all waves

  if constexpr (EPI == 2){
    if (t < BM) gate_lds[t] = 1.f / (1.f + __expf(-(gate_lds[t] + bg2p[0])));
  }

  // ---------------- phase B: C = H1 @ W2 + b2 ----------------
  const int colb2 = w * (N2 / 8);
  const bf16* cp0 = W2p + ((size_t)((colb2>>4)    ) * NKB) * 512 + lo8;
  const bf16* cp1 = W2p + ((size_t)((colb2>>4) + 1) * NKB) * 512 + lo8;

#pragma unroll
  for (int mf = 0; mf < MF; ++mf)
#pragma unroll
    for (int j = 0; j < 2; ++j)
#pragma unroll
      for (int r = 0; r < 4; ++r) acc[mf][j][r] = 0.f;

#pragma unroll
  for (int kt = 0; kt < NKB; ++kt){
    const bf16x8 c0 = *reinterpret_cast<const bf16x8*>(cp0 + kt*512);
    const bf16x8 c1 = *reinterpret_cast<const bf16x8*>(cp1 + kt*512);
#pragma unroll
    for (int mf = 0; mf < MF; ++mf){
      const int row = mf*16 + fRow;
      const unsigned off = ((unsigned)(row*N1 + kt*32 + kOff)*2u) ^ ((unsigned)(row & 7) << 4);
      const bf16x8 af = *reinterpret_cast<const bf16x8*>(smem + off);
      acc[mf][0] = __builtin_amdgcn_mfma_f32_16x16x32_bf16(af, c0, acc[mf][0], 0, 0, 0);
      acc[mf][1] = __builtin_amdgcn_mfma_f32_16x16x32_bf16(af, c1, acc[mf][1], 0, 0, 0);
    }
  }

  if constexpr (EPI == 2){
    // scatter epilogue: inc[(b*NN + slot[tok])*D + col] += (C + b2) * gate
    __syncthreads();                    // gate_lds sigmoid + all H1 reads done
    const int bb = bm0 >> 12;           // batch (BM divides 4096)
#pragma unroll
    for (int mf = 0; mf < MF; ++mf){
      float gr[4]; int sl[4];
#pragma unroll
      for (int r = 0; r < 4; ++r){
        const int row = mf*16 + kq*4 + r;
        gr[r] = gate_lds[row];
        sl[r] = slot_lds[row];
      }
#pragma unroll
      for (int j = 0; j < 2; ++j){
        const int col = colb2 + j*16 + fRow;
        const float bvx = b2[col];
#pragma unroll
        for (int r = 0; r < 4; ++r)
          atomicAdd(incp + ((size_t)(bb*NN + sl[r]))*D + col, (acc[mf][j][r] + bvx) * gr[r]);
      }
    }
  } else {
    // fused residual + LayerNorm (BM=32, rows complete across the 8 waves' cols)
    float vals[MF][2][4];
#pragma unroll
    for (int mf = 0; mf < MF; ++mf){
      const int row0 = mf*16 + kq*4;
#pragma unroll
      for (int j = 0; j < 2; ++j){
        const int col = colb2 + j*16 + fRow;
        const float bvx = b2[col];
#pragma unroll
        for (int r = 0; r < 4; ++r)
          vals[mf][j][r] = S[(size_t)(bm0 + row0 + r)*N2 + col] + acc[mf][j][r] + bvx;
      }
    }
    __syncthreads();                    // all H1 reads done; smem reusable
    float* red = (float*)smem;          // [BM rows][8 waves][2]
#pragma unroll
    for (int mf = 0; mf < MF; ++mf)
#pragma unroll
      for (int r = 0; r < 4; ++r){
        float s = 0.f, q = 0.f;
#pragma unroll
        for (int j = 0; j < 2; ++j){ s += vals[mf][j][r]; q += vals[mf][j][r]*vals[mf][j][r]; }
        s += __shfl_xor(s, 1); s += __shfl_xor(s, 2); s += __shfl_xor(s, 4); s += __shfl_xor(s, 8);
        q += __shfl_xor(q, 1); q += __shfl_xor(q, 2); q += __shfl_xor(q, 4); q += __shfl_xor(q, 8);
        if (fRow == 0){
          const int row = mf*16 + kq*4 + r;
          red[(row*8 + w)*2 + 0] = s;
          red[(row*8 + w)*2 + 1] = q;
        }
      }
    __syncthreads();
    float* mur = (float*)smem + BM*8*2;
    if (t < BM){
      float s = 0.f, q = 0.f;
      for (int w2 = 0; w2 < 8; w2++){ s += red[(t*8 + w2)*2]; q += red[(t*8 + w2)*2 + 1]; }
      const float mu = s * (1.f/256.f);
      const float var = q * (1.f/256.f) - mu*mu;
      mur[t*2] = mu; mur[t*2 + 1] = rsqrtf(var + 1e-5f);
    }
    __syncthreads();
#pragma unroll
    for (int mf = 0; mf < MF; ++mf){
      const int row0 = mf*16 + kq*4;
#pragma unroll
      for (int j = 0; j < 2; ++j){
        const int col = colb2 + j*16 + fRow;
        const float lw = lnw[col], lb = lnb[col];
#pragma unroll
        for (int r = 0; r < 4; ++r){
          const int row = row0 + r;
          ((float*)Cout)[(size_t)(bm0 + row)*N2 + col] =
              (vals[mf][j][r] - mur[row*2]) * mur[row*2 + 1] * lw + lb;
        }
      }
    }
  }
}

// fp32 routing GEMM + fused X bf16-packing (R17, kept)
__global__ __launch_bounds__(256) void route5_k(const float* __restrict__ X,
                                                const float* __restrict__ Wcat,
                                                int* __restrict__ slot_out,
                                                bf16* __restrict__ Xp)
{
  __shared__ float lds[128 * 84];
  float* Xs = lds;                      // [16][136]
  float* Ws = lds + 16 * 136;           // [16][80]
  float* Cs = lds;                      // [128][84] epilogue alias

  const int t = threadIdx.x;
  const int tok0 = blockIdx.x * 128;
  const int cq = t & 15;
  const int tg = t >> 4;
  const int stok = t >> 2, skq = t & 3;

  const float* xsrc0 = X + (size_t)(tok0 + stok) * D + 4*skq;
  const float* xsrc1 = X + (size_t)(tok0 + 64 + stok) * D + 4*skq;
  const int wrow0 = t / 20,        wc0 = t - wrow0*20;
  const int wrow1 = (256+t) / 20,  wc1 = (256+t) - wrow1*20;

  float accg[8][4] = {};
  float accs[8] = {};

  auto packw = [&](int tok, int k0, float4 v){
    const int ng = tok >> 4, f = tok & 15;
    const int kt = k0 >> 5, q = (k0 >> 3) & 3, e0 = k0 & 7;
    const size_t off = ((size_t)(ng*8 + kt)*64 + (f*4 + q))*8 + e0;
    ushort4 u;
    u.x = __bfloat16_as_ushort(__float2bfloat16(v.x));
    u.y = __bfloat16_as_ushort(__float2bfloat16(v.y));
    u.z = __bfloat16_as_ushort(__float2bfloat16(v.z));
    u.w = __bfloat16_as_ushort(__float2bfloat16(v.w));
    *reinterpret_cast<ushort4*>(Xp + off) = u;
  };

  float4 xr0 = *reinterpret_cast<const float4*>(xsrc0);
  float4 xr1 = *reinterpret_cast<const float4*>(xsrc1);
  float4 wr0 = *reinterpret_cast<const float4*>(Wcat + (size_t)wrow0*80 + 4*wc0);
  float4 wr1;
  if (t < 64) wr1 = *reinterpret_cast<const float4*>(Wcat + (size_t)wrow1*80 + 4*wc1);

  for (int kt = 0; kt < 16; ++kt){
    __syncthreads();
    Xs[(4*skq+0)*136 + stok] = xr0.x;
    Xs[(4*skq+1)*136 + stok] = xr0.y;
    Xs[(4*skq+2)*136 + stok] = xr0.z;
    Xs[(4*skq+3)*136 + stok] = xr0.w;
    Xs[(4*skq+0)*136 + 64 + stok] = xr1.x;
    Xs[(4*skq+1)*136 + 64 + stok] = xr1.y;
    Xs[(4*skq+2)*136 + 64 + stok] = xr1.z;
    Xs[(4*skq+3)*136 + 64 + stok] = xr1.w;
    *reinterpret_cast<float4*>(&Ws[wrow0*80 + 4*wc0]) = wr0;
    if (t < 64) *reinterpret_cast<float4*>(&Ws[wrow1*80 + 4*wc1]) = wr1;
    packw(tok0 + stok,      kt*16 + 4*skq, xr0);
    packw(tok0 + 64 + stok, kt*16 + 4*skq, xr1);
    __syncthreads();
    if (kt < 15){
      const int ko = (kt+1)*16;
      xr0 = *reinterpret_cast<const float4*>(xsrc0 + ko);
      xr1 = *reinterpret_cast<const float4*>(xsrc1 + ko);
      wr0 = *reinterpret_cast<const float4*>(Wcat + (size_t)(ko + wrow0)*80 + 4*wc0);
      if (t < 64) wr1 = *reinterpret_cast<const float4*>(Wcat + (size_t)(ko + wrow1)*80 + 4*wc1);
    }
#pragma unroll
    for (int k = 0; k < 16; ++k){
      const float4 xa = *reinterpret_cast<const float4*>(&Xs[k*136 + tg*8]);
      const float4 xb = *reinterpret_cast<const float4*>(&Xs[k*136 + tg*8 + 4]);
      const float4 wq = *reinterpret_cast<const float4*>(&Ws[k*80 + 4*cq]);
      const float wsv = Ws[k*80 + 64 + cq];
      const float xv[8] = {xa.x, xa.y, xa.z, xa.w, xb.x, xb.y, xb.z, xb.w};
#pragma unroll
      for (int m = 0; m < 8; m++){
        accg[m][0] = fmaf(xv[m], wq.x, accg[m][0]);
        accg[m][1] = fmaf(xv[m], wq.y, accg[m][1]);
        accg[m][2] = fmaf(xv[m], wq.z, accg[m][2]);
        accg[m][3] = fmaf(xv[m], wq.w, accg[m][3]);
        accs[m]    = fmaf(xv[m], wsv,  accs[m]);
      }
    }
  }

  __syncthreads();
#pragma unroll
  for (int m = 0; m < 8; m++){
    const int tok = tg*8 + m;
    Cs[tok*84 + 4*cq + 0] = accg[m][0];
    Cs[tok*84 + 4*cq + 1] = accg[m][1];
    Cs[tok*84 + 4*cq + 2] = accg[m][2];
    Cs[tok*84 + 4*cq + 3] = accg[m][3];
    Cs[tok*84 + 64 + cq]  = accs[m];
  }
  __syncthreads();
  if (t < 128){
    const float* row = &Cs[t * 84];
    float bg = row[0]; int big = 0;
    for (int g = 1; g < 64; ++g){ const float v = row[g]; if (v > bg){ bg = v; big = g; } }
    float bs = row[64]; int bis = 0;
    for (int s2 = 1; s2 < 16; ++s2){ const float v = row[64 + s2]; if (v > bs){ bs = v; bis = s2; } }
    slot_out[tok0 + t] = big * KK + bis;
  }
}

} // namespace

extern "C" void kernel_launch(void* const* d_in, const int* in_sizes, int n_in,
                              void* d_out, int out_size, void* d_ws, size_t ws_size,
                              hipStream_t stream)
{
  (void)in_sizes; (void)n_in; (void)out_size; (void)ws_size;
  const float* X   = (const float*)d_in[0];
  const float* S   = (const float*)d_in[1];
  const float* Wgr = (const float*)d_in[2];
  const float* Wsl = (const float*)d_in[3];
  const float* Wm1 = (const float*)d_in[4];
  const float* bm1 = (const float*)d_in[5];
  const float* Wm2 = (const float*)d_in[6];
  const float* bm2 = (const float*)d_in[7];
  const float* Wg1 = (const float*)d_in[8];
  const float* bg1 = (const float*)d_in[9];
  const float* Wg2 = (const float*)d_in[10];
  const float* bg2 = (const float*)d_in[11];
  const float* Wu1 = (const float*)d_in[12];
  const float* bu1 = (const float*)d_in[13];
  const float* Wu2 = (const float*)d_in[14];
  const float* bu2 = (const float*)d_in[15];
  const float* lnw = (const float*)d_in[16];
  const float* lnb = (const float*)d_in[17];
  float* out = (float*)d_out;

  char* ws = (char*)d_ws;
  bf16* Xp   = (bf16*)(ws + 0);                   // 16,777,216 B (packed X)
  bf16* W1p  = (bf16*)(ws + 67108864);            // 393,216 B (packed [Wm1|Wg1], NK=8)
  bf16* W2p  = (bf16*)(ws + 67108864 + 393216);   // 262,144 B (packed Wm2, NK=16)
  bf16* Wu1p = (bf16*)(ws + 67108864 + 655360);   // 524,288 B (packed Wu1, NK=16)
  bf16* Wu2p = (bf16*)(ws + 67108864 + 1179648);  // 262,144 B (packed Wu2, NK=16)
  int*   slot = (int*)  (ws + 68550656);          // 131,072 B
  float* inc  = (float*)(ws + 68812800);          // 8,388,608 B
  float* Wcat = (float*)(ws + 77201408);          // 81,920 B
  float* bcat = (float*)(ws + 77201408 + 81920);  // 3,072 B

  prep_w_k<<<(742144 + 255)/256, 256, 0, stream>>>(Wm1, Wg1, Wm2, Wu1, Wu2, Wgr, Wsl, bm1, bg1,
                                                   W1p, W2p, Wu1p, Wu2p, Wcat, bcat);

  // routing + fused X bf16 packing
  route5_k<<<NTOK/128, 256, 0, stream>>>(X, Wcat, slot, Xp);
  hipMemsetAsync(inc, 0, (size_t)NSLOT*D*sizeof(float), stream);

  // fused msg MLP + gate + scatter: inc[slot] += (gelu(X@Wm1+bm1)@Wm2+bm2) * sigmoid(gate)
  fused2_k<256, 512, 256, 256, 64, 2, 0><<<NTOK/64, 512, 0, stream>>>(
      Xp, W1p, bcat, W2p, bm2, nullptr,
      nullptr, nullptr, nullptr, Wg2, slot, bg2, inc);

  // fused slot-update MLP + residual + LayerNorm -> out
  // (A = [S | inc] converted in-register during LDS staging; pack_h deleted)
  fused2_k<512, 512, 0, 256, 32, 1, 1><<<NSLOT/32, 512, 0, stream>>>(
      nullptr, Wu1p, bu1, Wu2p, bu2, out,
      S, lnw, lnb, nullptr, nullptr, nullptr, inc);
}

// Round 20
// 138.705 us; speedup vs baseline: 1.2526x; 1.0176x over previous
//
#include <hip/hip_runtime.h>
#include <hip/hip_bf16.h>

using bf16 = __hip_bfloat16;
typedef __attribute__((ext_vector_type(8))) __bf16 bf16x8;
typedef __attribute__((ext_vector_type(4))) float f32x4;

namespace {

constexpr int D     = 256;
constexpr int NTOK  = 32768;   // B*L
constexpr int NSLOT = 8192;    // B*N
constexpr int GG    = 64;
constexpr int KK    = 16;
constexpr int NN    = 1024;

// Abramowitz–Stegun 7.1.26 rational erf, |err| <= 1.5e-7
__device__ __forceinline__ float erf_fast(float x){
  const float ax = fabsf(x);
  const float tt = 1.0f / fmaf(0.3275911f, ax, 1.0f);
  float p = fmaf(1.061405429f, tt, -1.453152027f);
  p = fmaf(p, tt, 1.421413741f);
  p = fmaf(p, tt, -0.284496736f);
  p = fmaf(p, tt, 0.254829592f);
  p *= tt;
  const float e = __expf(-ax*ax);
  const float r = 1.0f - p*e;
  return copysignf(r, x);
}

__device__ __forceinline__ float gelu_f(float x){
  return 0.5f * x * (1.0f + erf_fast(x * 0.70710678118654752f));
}

__device__ __forceinline__ void async_ld16(const void* g, void* l){
  typedef const __attribute__((address_space(1))) unsigned int gu32;
  typedef __attribute__((address_space(3))) unsigned int lu32;
  __builtin_amdgcn_global_load_lds((gu32*)g, (lu32*)l, 16, 0, 0);
}

struct alignas(16) ushort8s { unsigned short v[8]; };

__device__ __forceinline__ ushort8s pack8(const float* src){
  const float4 f0 = reinterpret_cast<const float4*>(src)[0];
  const float4 f1 = reinterpret_cast<const float4*>(src)[1];
  ushort8s u;
  u.v[0] = __bfloat16_as_ushort(__float2bfloat16(f0.x));
  u.v[1] = __bfloat16_as_ushort(__float2bfloat16(f0.y));
  u.v[2] = __bfloat16_as_ushort(__float2bfloat16(f0.z));
  u.v[3] = __bfloat16_as_ushort(__float2bfloat16(f0.w));
  u.v[4] = __bfloat16_as_ushort(__float2bfloat16(f1.x));
  u.v[5] = __bfloat16_as_ushort(__float2bfloat16(f1.y));
  u.v[6] = __bfloat16_as_ushort(__float2bfloat16(f1.z));
  u.v[7] = __bfloat16_as_ushort(__float2bfloat16(f1.w));
  return u;
}

// ---------------------------------------------------------------------------
// Fragment-packed layout: logical Wt[N][K] bf16 stored as 1KB tiles
//   flat = ((ng*NK + kt)*64 + fRow*4 + kq)*8 + e
// ---------------------------------------------------------------------------

__global__ void prep_w_k(const float* __restrict__ Wm1, const float* __restrict__ Wg1,
                         const float* __restrict__ Wm2, const float* __restrict__ Wu1,
                         const float* __restrict__ Wu2, const float* __restrict__ Wgr,
                         const float* __restrict__ Wsl, const float* __restrict__ bm1,
                         const float* __restrict__ bg1,
                         bf16* __restrict__ W1p, bf16* __restrict__ W2p,
                         bf16* __restrict__ Wu1p, bf16* __restrict__ Wu2p,
                         float* __restrict__ Wcat, float* __restrict__ bcat)
{
  const int idx = blockIdx.x*256 + threadIdx.x;
  if (idx < 196608){                                    // W1cat packed, NK=8
    const int e = idx&7, q = (idx>>3)&3, f = (idx>>5)&15, tile = idx>>9;
    const int kt = tile&7, ng = tile>>3;
    const int n = ng*16+f, k = kt*32+q*8+e;
    W1p[idx] = __float2bfloat16(n < 512 ? Wm1[k*512+n] : Wg1[k*256+(n-512)]);
  } else if (idx < 327680){                             // Wm2 packed, NK=16
    const int i = idx-196608;
    const int e = i&7, q = (i>>3)&3, f = (i>>5)&15, tile = i>>9;
    const int kt = tile&15, ng = tile>>4;
    W2p[i] = __float2bfloat16(Wm2[(kt*32+q*8+e)*256 + ng*16+f]);
  } else if (idx < 589824){                             // Wu1 packed, NK=16
    const int i = idx-327680;
    const int e = i&7, q = (i>>3)&3, f = (i>>5)&15, tile = i>>9;
    const int kt = tile&15, ng = tile>>4;
    Wu1p[i] = __float2bfloat16(Wu1[(kt*32+q*8+e)*512 + ng*16+f]);
  } else if (idx < 720896){                             // Wu2 packed, NK=16
    const int i = idx-589824;
    const int e = i&7, q = (i>>3)&3, f = (i>>5)&15, tile = i>>9;
    const int kt = tile&15, ng = tile>>4;
    Wu2p[i] = __float2bfloat16(Wu2[(kt*32+q*8+e)*256 + ng*16+f]);
  } else if (idx < 741376){                             // Wcat [256][80] fp32 (k-major)
    const int i = idx - 720896, k = i / 80, c = i - k*80;
    Wcat[i] = (c < GG) ? Wgr[k*GG + c] : Wsl[k*KK + (c - GG)];
  } else if (idx < 742144){                             // bcat [768]
    const int c = idx - 741376;
    bcat[c] = (c < 512) ? bm1[c] : bg1[c - 512];
  }
}

// ---------------------------------------------------------------------------
// Fused 2-layer MLP, fragment-packed operands, A-tile staged in LDS.
// (unchanged from R18)
// ---------------------------------------------------------------------------
template<int K, int N1, int NG, int N2, int BM, int EPI, int AF32>
__global__ __launch_bounds__(512, 1) void fused2_k(
    const bf16* __restrict__ Ap,
    const bf16* __restrict__ W1p, const float* __restrict__ b1,
    const bf16* __restrict__ W2p, const float* __restrict__ b2,
    void* __restrict__ Cout,
    const float* __restrict__ S, const float* __restrict__ lnw, const float* __restrict__ lnb,
    const float* __restrict__ Wg2,
    const int* __restrict__ slotp, const float* __restrict__ bg2p, float* __restrict__ incp)
{
  constexpr int SLICE = (N1 + NG) / 8;  // cols per wave, phase A (96 or 64)
  constexpr int SP    = SLICE / 32;     // 32-col sub-phases
  constexpr int MF    = BM / 16;        // M fragments (4 or 2)
  constexpr int NKA   = K / 32;
  constexpr int NKB   = N1 / 32;
  constexpr int H1B   = BM * N1 * 2;    // LDS bytes for H1
  constexpr int AB    = BM * K * 2;     // LDS bytes for A tile (32KB both kernels)
  __shared__ alignas(16) char smem[H1B];
  __shared__ alignas(16) char As_lds[AB];
  __shared__ float gate_lds[EPI == 2 ? BM : 1];
  __shared__ int   slot_lds[EPI == 2 ? BM : 1];

  const int t = threadIdx.x, lane = t & 63, w = t >> 6;
  const int fRow = lane & 15, kq = lane >> 4, kOff = kq * 8;
  const int lo8 = (fRow*4 + kq) * 8;    // per-lane elem offset within a 1KB tile
  const int bm0 = blockIdx.x * BM;

  // ---- stage A tile ----
  if constexpr (AF32 == 0){
    const bf16* Asrc = Ap + (size_t)(bm0 >> 4) * NKA * 512;
#pragma unroll
    for (int u = t; u < AB/16; u += 512)
      async_ld16(Asrc + u*8, (bf16*)As_lds + u*8);
    if constexpr (EPI == 2){
      if (t < BM){ gate_lds[t] = 0.f; slot_lds[t] = slotp[bm0 + t]; }
    }
    asm volatile("s_waitcnt vmcnt(0)" ::: "memory");
    __syncthreads();
  } else {
    // reg-path: [S | incp] f32 -> bf16 packed chunks
#pragma unroll
    for (int u = t; u < AB/16; u += 512){
      const int q = u & 3, f = (u >> 2) & 15, kt = (u >> 6) % NKA, ngl = u / (64*NKA);
      const int r = bm0 + ngl*16 + f, c = kt*32 + q*8;
      const float* src = (c < 256) ? (S + (size_t)r*256 + c)
                                   : (incp + (size_t)r*256 + (c - 256));
      reinterpret_cast<ushort8s*>(As_lds)[u] = pack8(src);
    }
    __syncthreads();
  }

  f32x4 acc[MF][2];                     // single accumulator, reused by phase B

  // ---------------- phase A ----------------
  for (int sp = 0; sp < SP; ++sp){
    const int colb = w * SLICE + sp * 32;
    const bf16* bp0 = W1p + ((size_t)((colb>>4)    ) * NKA) * 512 + lo8;
    const bf16* bp1 = W1p + ((size_t)((colb>>4) + 1) * NKA) * 512 + lo8;

#pragma unroll
    for (int mf = 0; mf < MF; ++mf)
#pragma unroll
      for (int j = 0; j < 2; ++j)
#pragma unroll
        for (int r = 0; r < 4; ++r) acc[mf][j][r] = 0.f;

#pragma unroll
    for (int kt = 0; kt < NKA; ++kt){
      const bf16x8 b0  = *reinterpret_cast<const bf16x8*>(bp0 + kt*512);
      const bf16x8 b1v = *reinterpret_cast<const bf16x8*>(bp1 + kt*512);
#pragma unroll
      for (int mf = 0; mf < MF; ++mf){
        const bf16x8 a = *reinterpret_cast<const bf16x8*>(
            (const bf16*)As_lds + ((mf*NKA + kt)*512 + lo8));
        acc[mf][0] = __builtin_amdgcn_mfma_f32_16x16x32_bf16(a, b0,  acc[mf][0], 0, 0, 0);
        acc[mf][1] = __builtin_amdgcn_mfma_f32_16x16x32_bf16(a, b1v, acc[mf][1], 0, 0, 0);
      }
    }

    // sub-phase epilogue: H1 write (swizzled) or gate accumulation into LDS
    if (NG == 0 || colb < N1){
#pragma unroll
      for (int mf = 0; mf < MF; ++mf){
#pragma unroll
        for (int j = 0; j < 2; ++j){
          const int col = colb + j*16 + fRow;
          const float bvx = b1[col];
#pragma unroll
          for (int r = 0; r < 4; ++r){
            const int row = mf*16 + kq*4 + r;
            const float v = gelu_f(acc[mf][j][r] + bvx);
            const unsigned off = ((unsigned)(row*N1 + col)*2u) ^ ((unsigned)(row & 7) << 4);
            *(bf16*)(smem + off) = __float2bfloat16(v);
          }
        }
      }
    } else if constexpr (NG > 0 && EPI == 2){
      const float b1v0 = b1[colb + fRow],       b1v1 = b1[colb + 16 + fRow];
      const float wg0  = Wg2[colb - N1 + fRow], wg1  = Wg2[colb - N1 + 16 + fRow];
#pragma unroll
      for (int mf = 0; mf < MF; ++mf){
#pragma unroll
        for (int r = 0; r < 4; ++r){
          float p = gelu_f(acc[mf][0][r] + b1v0) * wg0
                  + gelu_f(acc[mf][1][r] + b1v1) * wg1;
          p += __shfl_xor(p, 1); p += __shfl_xor(p, 2);
          p += __shfl_xor(p, 4); p += __shfl_xor(p, 8);
          if (fRow == 0) atomicAdd(&gate_lds[mf*16 + kq*4 + r], p);
        }
      }
    }
  }
  __syncthreads();   // H1 + gate partials complete, visible to all waves

  if constexpr (EPI == 2){
    if (t < BM) gate_lds[t] = 1.f / (1.f + __expf(-(gate_lds[t] + bg2p[0])));
  }

  // ---------------- phase B: C = H1 @ W2 + b2 ----------------
  const int colb2 = w * (N2 / 8);
  const bf16* cp0 = W2p + ((size_t)((colb2>>4)    ) * NKB) * 512 + lo8;
  const bf16* cp1 = W2p + ((size_t)((colb2>>4) + 1) * NKB) * 512 + lo8;

#pragma unroll
  for (int mf = 0; mf < MF; ++mf)
#pragma unroll
    for (int j = 0; j < 2; ++j)
#pragma unroll
      for (int r = 0; r < 4; ++r) acc[mf][j][r] = 0.f;

#pragma unroll
  for (int kt = 0; kt < NKB; ++kt){
    const bf16x8 c0 = *reinterpret_cast<const bf16x8*>(cp0 + kt*512);
    const bf16x8 c1 = *reinterpret_cast<const bf16x8*>(cp1 + kt*512);
#pragma unroll
    for (int mf = 0; mf < MF; ++mf){
      const int row = mf*16 + fRow;
      const unsigned off = ((unsigned)(row*N1 + kt*32 + kOff)*2u) ^ ((unsigned)(row & 7) << 4);
      const bf16x8 af = *reinterpret_cast<const bf16x8*>(smem + off);
      acc[mf][0] = __builtin_amdgcn_mfma_f32_16x16x32_bf16(af, c0, acc[mf][0], 0, 0, 0);
      acc[mf][1] = __builtin_amdgcn_mfma_f32_16x16x32_bf16(af, c1, acc[mf][1], 0, 0, 0);
    }
  }

  if constexpr (EPI == 2){
    // scatter epilogue: inc[(b*NN + slot[tok])*D + col] += (C + b2) * gate
    __syncthreads();
    const int bb = bm0 >> 12;           // batch (BM divides 4096)
#pragma unroll
    for (int mf = 0; mf < MF; ++mf){
      float gr[4]; int sl[4];
#pragma unroll
      for (int r = 0; r < 4; ++r){
        const int row = mf*16 + kq*4 + r;
        gr[r] = gate_lds[row];
        sl[r] = slot_lds[row];
      }
#pragma unroll
      for (int j = 0; j < 2; ++j){
        const int col = colb2 + j*16 + fRow;
        const float bvx = b2[col];
#pragma unroll
        for (int r = 0; r < 4; ++r)
          atomicAdd(incp + ((size_t)(bb*NN + sl[r]))*D + col, (acc[mf][j][r] + bvx) * gr[r]);
      }
    }
  } else {
    // fused residual + LayerNorm (BM=32, rows complete across the 8 waves' cols)
    float vals[MF][2][4];
#pragma unroll
    for (int mf = 0; mf < MF; ++mf){
      const int row0 = mf*16 + kq*4;
#pragma unroll
      for (int j = 0; j < 2; ++j){
        const int col = colb2 + j*16 + fRow;
        const float bvx = b2[col];
#pragma unroll
        for (int r = 0; r < 4; ++r)
          vals[mf][j][r] = S[(size_t)(bm0 + row0 + r)*N2 + col] + acc[mf][j][r] + bvx;
      }
    }
    __syncthreads();
    float* red = (float*)smem;          // [BM rows][8 waves][2]
#pragma unroll
    for (int mf = 0; mf < MF; ++mf)
#pragma unroll
      for (int r = 0; r < 4; ++r){
        float s = 0.f, q = 0.f;
#pragma unroll
        for (int j = 0; j < 2; ++j){ s += vals[mf][j][r]; q += vals[mf][j][r]*vals[mf][j][r]; }
        s += __shfl_xor(s, 1); s += __shfl_xor(s, 2); s += __shfl_xor(s, 4); s += __shfl_xor(s, 8);
        q += __shfl_xor(q, 1); q += __shfl_xor(q, 2); q += __shfl_xor(q, 4); q += __shfl_xor(q, 8);
        if (fRow == 0){
          const int row = mf*16 + kq*4 + r;
          red[(row*8 + w)*2 + 0] = s;
          red[(row*8 + w)*2 + 1] = q;
        }
      }
    __syncthreads();
    float* mur = (float*)smem + BM*8*2;
    if (t < BM){
      float s = 0.f, q = 0.f;
      for (int w2 = 0; w2 < 8; w2++){ s += red[(t*8 + w2)*2]; q += red[(t*8 + w2)*2 + 1]; }
      const float mu = s * (1.f/256.f);
      const float var = q * (1.f/256.f) - mu*mu;
      mur[t*2] = mu; mur[t*2 + 1] = rsqrtf(var + 1e-5f);
    }
    __syncthreads();
#pragma unroll
    for (int mf = 0; mf < MF; ++mf){
      const int row0 = mf*16 + kq*4;
#pragma unroll
      for (int j = 0; j < 2; ++j){
        const int col = colb2 + j*16 + fRow;
        const float lw = lnw[col], lb = lnb[col];
#pragma unroll
        for (int r = 0; r < 4; ++r){
          const int row = row0 + r;
          ((float*)Cout)[(size_t)(bm0 + row)*N2 + col] =
              (vals[mf][j][r] - mur[row*2]) * mur[row*2 + 1] * lw + lb;
        }
      }
    }
  }
}

// fp32 routing GEMM + fused X bf16-packing. 64 tokens/block (grid 512 ->
// 2 blocks/CU, 2 waves/SIMD; R18's 128-tok config ran 1 block/CU with zero
// cross-block overlap). Per-(tok,col) fp32 accumulation order and first-win
// argmax identical to route5 -> bit-identical slots.
__global__ __launch_bounds__(256) void route6_k(const float* __restrict__ X,
                                                const float* __restrict__ Wcat,
                                                int* __restrict__ slot_out,
                                                bf16* __restrict__ Xp)
{
  __shared__ float lds[64 * 84];        // 21504B; main loop uses first 2368 floats
  float* Xs = lds;                      // [16][68]
  float* Ws = lds + 16 * 68;            // [16][80]
  float* Cs = lds;                      // [64][84] epilogue alias

  const int t = threadIdx.x;
  const int tok0 = blockIdx.x * 64;
  const int cq = t & 15;
  const int tg = t >> 4;                // 0..15 -> tokens tg*4..tg*4+3
  const int stok = t >> 2, skq = t & 3;

  const float* xsrc = X + (size_t)(tok0 + stok) * D + 4*skq;
  const int wrow0 = t / 20,        wc0 = t - wrow0*20;
  const int wrow1 = (256+t) / 20,  wc1 = (256+t) - wrow1*20;

  float accg[4][4] = {};
  float accs[4] = {};

  auto packw = [&](int tok, int k0, float4 v){
    const int ng = tok >> 4, f = tok & 15;
    const int kt = k0 >> 5, q = (k0 >> 3) & 3, e0 = k0 & 7;
    const size_t off = ((size_t)(ng*8 + kt)*64 + (f*4 + q))*8 + e0;
    ushort4 u;
    u.x = __bfloat16_as_ushort(__float2bfloat16(v.x));
    u.y = __bfloat16_as_ushort(__float2bfloat16(v.y));
    u.z = __bfloat16_as_ushort(__float2bfloat16(v.z));
    u.w = __bfloat16_as_ushort(__float2bfloat16(v.w));
    *reinterpret_cast<ushort4*>(Xp + off) = u;
  };

  float4 xr = *reinterpret_cast<const float4*>(xsrc);
  float4 wr0 = *reinterpret_cast<const float4*>(Wcat + (size_t)wrow0*80 + 4*wc0);
  float4 wr1;
  if (t < 64) wr1 = *reinterpret_cast<const float4*>(Wcat + (size_t)wrow1*80 + 4*wc1);

  for (int kt = 0; kt < 16; ++kt){
    __syncthreads();
    Xs[(4*skq+0)*68 + stok] = xr.x;
    Xs[(4*skq+1)*68 + stok] = xr.y;
    Xs[(4*skq+2)*68 + stok] = xr.z;
    Xs[(4*skq+3)*68 + stok] = xr.w;
    *reinterpret_cast<float4*>(&Ws[wrow0*80 + 4*wc0]) = wr0;
    if (t < 64) *reinterpret_cast<float4*>(&Ws[wrow1*80 + 4*wc1]) = wr1;
    packw(tok0 + stok, kt*16 + 4*skq, xr);
    __syncthreads();
    if (kt < 15){
      const int ko = (kt+1)*16;
      xr  = *reinterpret_cast<const float4*>(xsrc + ko);
      wr0 = *reinterpret_cast<const float4*>(Wcat + (size_t)(ko + wrow0)*80 + 4*wc0);
      if (t < 64) wr1 = *reinterpret_cast<const float4*>(Wcat + (size_t)(ko + wrow1)*80 + 4*wc1);
    }
#pragma unroll
    for (int k = 0; k < 16; ++k){
      const float4 xa = *reinterpret_cast<const float4*>(&Xs[k*68 + tg*4]);
      const float4 wq = *reinterpret_cast<const float4*>(&Ws[k*80 + 4*cq]);
      const float wsv = Ws[k*80 + 64 + cq];
      const float xv[4] = {xa.x, xa.y, xa.z, xa.w};
#pragma unroll
      for (int m = 0; m < 4; m++){
        accg[m][0] = fmaf(xv[m], wq.x, accg[m][0]);
        accg[m][1] = fmaf(xv[m], wq.y, accg[m][1]);
        accg[m][2] = fmaf(xv[m], wq.z, accg[m][2]);
        accg[m][3] = fmaf(xv[m], wq.w, accg[m][3]);
        accs[m]    = fmaf(xv[m], wsv,  accs[m]);
      }
    }
  }

  __syncthreads();
#pragma unroll
  for (int m = 0; m < 4; m++){
    const int tok = tg*4 + m;
    Cs[tok*84 + 4*cq + 0] = accg[m][0];
    Cs[tok*84 + 4*cq + 1] = accg[m][1];
    Cs[tok*84 + 4*cq + 2] = accg[m][2];
    Cs[tok*84 + 4*cq + 3] = accg[m][3];
    Cs[tok*84 + 64 + cq]  = accs[m];
  }
  __syncthreads();
  if (t < 64){
    const float* row = &Cs[t * 84];
    float bg = row[0]; int big = 0;
    for (int g = 1; g < 64; ++g){ const float v = row[g]; if (v > bg){ bg = v; big = g; } }
    float bs = row[64]; int bis = 0;
    for (int s2 = 1; s2 < 16; ++s2){ const float v = row[64 + s2]; if (v > bs){ bs = v; bis = s2; } }
    slot_out[tok0 + t] = big * KK + bis;
  }
}

} // namespace

extern "C" void kernel_launch(void* const* d_in, const int* in_sizes, int n_in,
                              void* d_out, int out_size, void* d_ws, size_t ws_size,
                              hipStream_t stream)
{
  (void)in_sizes; (void)n_in; (void)out_size; (void)ws_size;
  const float* X   = (const float*)d_in[0];
  const float* S   = (const float*)d_in[1];
  const float* Wgr = (const float*)d_in[2];
  const float* Wsl = (const float*)d_in[3];
  const float* Wm1 = (const float*)d_in[4];
  const float* bm1 = (const float*)d_in[5];
  const float* Wm2 = (const float*)d_in[6];
  const float* bm2 = (const float*)d_in[7];
  const float* Wg1 = (const float*)d_in[8];
  const float* bg1 = (const float*)d_in[9];
  const float* Wg2 = (const float*)d_in[10];
  const float* bg2 = (const float*)d_in[11];
  const float* Wu1 = (const float*)d_in[12];
  const float* bu1 = (const float*)d_in[13];
  const float* Wu2 = (const float*)d_in[14];
  const float* bu2 = (const float*)d_in[15];
  const float* lnw = (const float*)d_in[16];
  const float* lnb = (const float*)d_in[17];
  float* out = (float*)d_out;

  char* ws = (char*)d_ws;
  bf16* Xp   = (bf16*)(ws + 0);                   // 16,777,216 B (packed X)
  bf16* W1p  = (bf16*)(ws + 67108864);            // 393,216 B (packed [Wm1|Wg1], NK=8)
  bf16* W2p  = (bf16*)(ws + 67108864 + 393216);   // 262,144 B (packed Wm2, NK=16)
  bf16* Wu1p = (bf16*)(ws + 67108864 + 655360);   // 524,288 B (packed Wu1, NK=16)
  bf16* Wu2p = (bf16*)(ws + 67108864 + 1179648);  // 262,144 B (packed Wu2, NK=16)
  int*   slot = (int*)  (ws + 68550656);          // 131,072 B
  float* inc  = (float*)(ws + 68812800);          // 8,388,608 B
  float* Wcat = (float*)(ws + 77201408);          // 81,920 B
  float* bcat = (float*)(ws + 77201408 + 81920);  // 3,072 B

  prep_w_k<<<(742144 + 255)/256, 256, 0, stream>>>(Wm1, Wg1, Wm2, Wu1, Wu2, Wgr, Wsl, bm1, bg1,
                                                   W1p, W2p, Wu1p, Wu2p, Wcat, bcat);

  // routing + fused X bf16 packing (64 tokens/block, 2 blocks/CU)
  route6_k<<<NTOK/64, 256, 0, stream>>>(X, Wcat, slot, Xp);
  hipMemsetAsync(inc, 0, (size_t)NSLOT*D*sizeof(float), stream);

  // fused msg MLP + gate + scatter: inc[slot] += (gelu(X@Wm1+bm1)@Wm2+bm2) * sigmoid(gate)
  fused2_k<256, 512, 256, 256, 64, 2, 0><<<NTOK/64, 512, 0, stream>>>(
      Xp, W1p, bcat, W2p, bm2, nullptr,
      nullptr, nullptr, nullptr, Wg2, slot, bg2, inc);

  // fused slot-update MLP + residual + LayerNorm -> out
  fused2_k<512, 512, 0, 256, 32, 1, 1><<<NSLOT/32, 512, 0, stream>>>(
      nullptr, Wu1p, bu1, Wu2p, bu2, out,
      S, lnw, lnb, nullptr, nullptr, nullptr, inc);
}

// Round 21
// 135.072 us; speedup vs baseline: 1.2863x; 1.0269x over previous
//
#include <hip/hip_runtime.h>
#include <hip/hip_bf16.h>

using bf16 = __hip_bfloat16;
typedef __attribute__((ext_vector_type(8))) __bf16 bf16x8;
typedef __attribute__((ext_vector_type(4))) float f32x4;

namespace {

constexpr int D     = 256;
constexpr int NTOK  = 32768;   // B*L
constexpr int NSLOT = 8192;    // B*N
constexpr int GG    = 64;
constexpr int KK    = 16;
constexpr int NN    = 1024;

// Abramowitz–Stegun 7.1.26 rational erf, |err| <= 1.5e-7
__device__ __forceinline__ float erf_fast(float x){
  const float ax = fabsf(x);
  const float tt = 1.0f / fmaf(0.3275911f, ax, 1.0f);
  float p = fmaf(1.061405429f, tt, -1.453152027f);
  p = fmaf(p, tt, 1.421413741f);
  p = fmaf(p, tt, -0.284496736f);
  p = fmaf(p, tt, 0.254829592f);
  p *= tt;
  const float e = __expf(-ax*ax);
  const float r = 1.0f - p*e;
  return copysignf(r, x);
}

__device__ __forceinline__ float gelu_f(float x){
  return 0.5f * x * (1.0f + erf_fast(x * 0.70710678118654752f));
}

__device__ __forceinline__ void async_ld16(const void* g, void* l){
  typedef const __attribute__((address_space(1))) unsigned int gu32;
  typedef __attribute__((address_space(3))) unsigned int lu32;
  __builtin_amdgcn_global_load_lds((gu32*)g, (lu32*)l, 16, 0, 0);
}

struct alignas(16) ushort8s { unsigned short v[8]; };

__device__ __forceinline__ ushort8s pack8(const float* src){
  const float4 f0 = reinterpret_cast<const float4*>(src)[0];
  const float4 f1 = reinterpret_cast<const float4*>(src)[1];
  ushort8s u;
  u.v[0] = __bfloat16_as_ushort(__float2bfloat16(f0.x));
  u.v[1] = __bfloat16_as_ushort(__float2bfloat16(f0.y));
  u.v[2] = __bfloat16_as_ushort(__float2bfloat16(f0.z));
  u.v[3] = __bfloat16_as_ushort(__float2bfloat16(f0.w));
  u.v[4] = __bfloat16_as_ushort(__float2bfloat16(f1.x));
  u.v[5] = __bfloat16_as_ushort(__float2bfloat16(f1.y));
  u.v[6] = __bfloat16_as_ushort(__float2bfloat16(f1.z));
  u.v[7] = __bfloat16_as_ushort(__float2bfloat16(f1.w));
  return u;
}

// ---------------------------------------------------------------------------
// Fragment-packed layout: logical Wt[N][K] bf16 stored as 1KB tiles
//   flat = ((ng*NK + kt)*64 + fRow*4 + kq)*8 + e
// ---------------------------------------------------------------------------

__global__ void prep_w_k(const float* __restrict__ Wm1, const float* __restrict__ Wg1,
                         const float* __restrict__ Wm2, const float* __restrict__ Wu1,
                         const float* __restrict__ Wu2, const float* __restrict__ Wgr,
                         const float* __restrict__ Wsl, const float* __restrict__ bm1,
                         const float* __restrict__ bg1,
                         bf16* __restrict__ W1p, bf16* __restrict__ W2p,
                         bf16* __restrict__ Wu1p, bf16* __restrict__ Wu2p,
                         float* __restrict__ Wcat, float* __restrict__ bcat)
{
  const int idx = blockIdx.x*256 + threadIdx.x;
  if (idx < 196608){                                    // W1cat packed, NK=8
    const int e = idx&7, q = (idx>>3)&3, f = (idx>>5)&15, tile = idx>>9;
    const int kt = tile&7, ng = tile>>3;
    const int n = ng*16+f, k = kt*32+q*8+e;
    W1p[idx] = __float2bfloat16(n < 512 ? Wm1[k*512+n] : Wg1[k*256+(n-512)]);
  } else if (idx < 327680){                             // Wm2 packed, NK=16
    const int i = idx-196608;
    const int e = i&7, q = (i>>3)&3, f = (i>>5)&15, tile = i>>9;
    const int kt = tile&15, ng = tile>>4;
    W2p[i] = __float2bfloat16(Wm2[(kt*32+q*8+e)*256 + ng*16+f]);
  } else if (idx < 589824){                             // Wu1 packed, NK=16
    const int i = idx-327680;
    const int e = i&7, q = (i>>3)&3, f = (i>>5)&15, tile = i>>9;
    const int kt = tile&15, ng = tile>>4;
    Wu1p[i] = __float2bfloat16(Wu1[(kt*32+q*8+e)*512 + ng*16+f]);
  } else if (idx < 720896){                             // Wu2 packed, NK=16
    const int i = idx-589824;
    const int e = i&7, q = (i>>3)&3, f = (i>>5)&15, tile = i>>9;
    const int kt = tile&15, ng = tile>>4;
    Wu2p[i] = __float2bfloat16(Wu2[(kt*32+q*8+e)*256 + ng*16+f]);
  } else if (idx < 741376){                             // Wcat [256][80] fp32 (k-major)
    const int i = idx - 720896, k = i / 80, c = i - k*80;
    Wcat[i] = (c < GG) ? Wgr[k*GG + c] : Wsl[k*KK + (c - GG)];
  } else if (idx < 742144){                             // bcat [768]
    const int c = idx - 741376;
    bcat[c] = (c < 512) ? bm1[c] : bg1[c - 512];
  }
}

// ---------------------------------------------------------------------------
// Fused 2-layer MLP, fragment-packed operands, A-tile staged in LDS.
// R20 change: W-fragments loaded in explicit 8-kt chunks into static arrays
// (16 bf16x8 = 128 VGPR) before each MFMA group — all 16 L2 loads issue
// back-to-back (one latency per chunk) instead of the compiler's shallow
// pipelined chain (VGPR_Count=104 showed only ~2-4 loads in flight).
// ---------------------------------------------------------------------------
template<int K, int N1, int NG, int N2, int BM, int EPI, int AF32>
__global__ __launch_bounds__(512, 1) void fused2_k(
    const bf16* __restrict__ Ap,
    const bf16* __restrict__ W1p, const float* __restrict__ b1,
    const bf16* __restrict__ W2p, const float* __restrict__ b2,
    void* __restrict__ Cout,
    const float* __restrict__ S, const float* __restrict__ lnw, const float* __restrict__ lnb,
    const float* __restrict__ Wg2,
    const int* __restrict__ slotp, const float* __restrict__ bg2p, float* __restrict__ incp)
{
  constexpr int SLICE = (N1 + NG) / 8;  // cols per wave, phase A (96 or 64)
  constexpr int SP    = SLICE / 32;     // 32-col sub-phases
  constexpr int MF    = BM / 16;        // M fragments (4 or 2)
  constexpr int NKA   = K / 32;
  constexpr int NKB   = N1 / 32;
  constexpr int CHA   = (NKA < 8) ? NKA : 8;   // W-load chunk, phase A
  constexpr int CHB   = (NKB < 8) ? NKB : 8;   // W-load chunk, phase B
  constexpr int H1B   = BM * N1 * 2;    // LDS bytes for H1
  constexpr int AB    = BM * K * 2;     // LDS bytes for A tile (32KB both kernels)
  __shared__ alignas(16) char smem[H1B];
  __shared__ alignas(16) char As_lds[AB];
  __shared__ float gate_lds[EPI == 2 ? BM : 1];
  __shared__ int   slot_lds[EPI == 2 ? BM : 1];

  const int t = threadIdx.x, lane = t & 63, w = t >> 6;
  const int fRow = lane & 15, kq = lane >> 4, kOff = kq * 8;
  const int lo8 = (fRow*4 + kq) * 8;    // per-lane elem offset within a 1KB tile
  const int bm0 = blockIdx.x * BM;

  // ---- stage A tile ----
  if constexpr (AF32 == 0){
    const bf16* Asrc = Ap + (size_t)(bm0 >> 4) * NKA * 512;
#pragma unroll
    for (int u = t; u < AB/16; u += 512)
      async_ld16(Asrc + u*8, (bf16*)As_lds + u*8);
    if constexpr (EPI == 2){
      if (t < BM){ gate_lds[t] = 0.f; slot_lds[t] = slotp[bm0 + t]; }
    }
    asm volatile("s_waitcnt vmcnt(0)" ::: "memory");
    __syncthreads();
  } else {
    // reg-path: [S | incp] f32 -> bf16 packed chunks
#pragma unroll
    for (int u = t; u < AB/16; u += 512){
      const int q = u & 3, f = (u >> 2) & 15, kt = (u >> 6) % NKA, ngl = u / (64*NKA);
      const int r = bm0 + ngl*16 + f, c = kt*32 + q*8;
      const float* src = (c < 256) ? (S + (size_t)r*256 + c)
                                   : (incp + (size_t)r*256 + (c - 256));
      reinterpret_cast<ushort8s*>(As_lds)[u] = pack8(src);
    }
    __syncthreads();
  }

  f32x4 acc[MF][2];                     // single accumulator, reused by phase B

  // ---------------- phase A ----------------
  for (int sp = 0; sp < SP; ++sp){
    const int colb = w * SLICE + sp * 32;
    const bf16* bp0 = W1p + ((size_t)((colb>>4)    ) * NKA) * 512 + lo8;
    const bf16* bp1 = W1p + ((size_t)((colb>>4) + 1) * NKA) * 512 + lo8;

#pragma unroll
    for (int mf = 0; mf < MF; ++mf)
#pragma unroll
      for (int j = 0; j < 2; ++j)
#pragma unroll
        for (int r = 0; r < 4; ++r) acc[mf][j][r] = 0.f;

#pragma unroll
    for (int kt0 = 0; kt0 < NKA; kt0 += CHA){
      bf16x8 bw[CHA][2];                // static-indexed -> registers
#pragma unroll
      for (int c = 0; c < CHA; ++c){
        bw[c][0] = *reinterpret_cast<const bf16x8*>(bp0 + (kt0 + c)*512);
        bw[c][1] = *reinterpret_cast<const bf16x8*>(bp1 + (kt0 + c)*512);
      }
#pragma unroll
      for (int c = 0; c < CHA; ++c){
        const int kt = kt0 + c;
#pragma unroll
        for (int mf = 0; mf < MF; ++mf){
          const bf16x8 a = *reinterpret_cast<const bf16x8*>(
              (const bf16*)As_lds + ((mf*NKA + kt)*512 + lo8));
          acc[mf][0] = __builtin_amdgcn_mfma_f32_16x16x32_bf16(a, bw[c][0], acc[mf][0], 0, 0, 0);
          acc[mf][1] = __builtin_amdgcn_mfma_f32_16x16x32_bf16(a, bw[c][1], acc[mf][1], 0, 0, 0);
        }
      }
    }

    // sub-phase epilogue: H1 write (swizzled) or gate accumulation into LDS
    if (NG == 0 || colb < N1){
#pragma unroll
      for (int mf = 0; mf < MF; ++mf){
#pragma unroll
        for (int j = 0; j < 2; ++j){
          const int col = colb + j*16 + fRow;
          const float bvx = b1[col];
#pragma unroll
          for (int r = 0; r < 4; ++r){
            const int row = mf*16 + kq*4 + r;
            const float v = gelu_f(acc[mf][j][r] + bvx);
            const unsigned off = ((unsigned)(row*N1 + col)*2u) ^ ((unsigned)(row & 7) << 4);
            *(bf16*)(smem + off) = __float2bfloat16(v);
          }
        }
      }
    } else if constexpr (NG > 0 && EPI == 2){
      const float b1v0 = b1[colb + fRow],       b1v1 = b1[colb + 16 + fRow];
      const float wg0  = Wg2[colb - N1 + fRow], wg1  = Wg2[colb - N1 + 16 + fRow];
#pragma unroll
      for (int mf = 0; mf < MF; ++mf){
#pragma unroll
        for (int r = 0; r < 4; ++r){
          float p = gelu_f(acc[mf][0][r] + b1v0) * wg0
                  + gelu_f(acc[mf][1][r] + b1v1) * wg1;
          p += __shfl_xor(p, 1); p += __shfl_xor(p, 2);
          p += __shfl_xor(p, 4); p += __shfl_xor(p, 8);
          if (fRow == 0) atomicAdd(&gate_lds[mf*16 + kq*4 + r], p);
        }
      }
    }
  }
  __syncthreads();   // H1 + gate partials complete, visible to all waves

  if constexpr (EPI == 2){
    if (t < BM) gate_lds[t] = 1.f / (1.f + __expf(-(gate_lds[t] + bg2p[0])));
  }

  // ---------------- phase B: C = H1 @ W2 + b2 ----------------
  const int colb2 = w * (N2 / 8);
  const bf16* cp0 = W2p + ((size_t)((colb2>>4)    ) * NKB) * 512 + lo8;
  const bf16* cp1 = W2p + ((size_t)((colb2>>4) + 1) * NKB) * 512 + lo8;

#pragma unroll
  for (int mf = 0; mf < MF; ++mf)
#pragma unroll
    for (int j = 0; j < 2; ++j)
#pragma unroll
      for (int r = 0; r < 4; ++r) acc[mf][j][r] = 0.f;

#pragma unroll
  for (int kt0 = 0; kt0 < NKB; kt0 += CHB){
    bf16x8 cw[CHB][2];                  // static-indexed -> registers
#pragma unroll
    for (int c = 0; c < CHB; ++c){
      cw[c][0] = *reinterpret_cast<const bf16x8*>(cp0 + (kt0 + c)*512);
      cw[c][1] = *reinterpret_cast<const bf16x8*>(cp1 + (kt0 + c)*512);
    }
#pragma unroll
    for (int c = 0; c < CHB; ++c){
      const int kt = kt0 + c;
#pragma unroll
      for (int mf = 0; mf < MF; ++mf){
        const int row = mf*16 + fRow;
        const unsigned off = ((unsigned)(row*N1 + kt*32 + kOff)*2u) ^ ((unsigned)(row & 7) << 4);
        const bf16x8 af = *reinterpret_cast<const bf16x8*>(smem + off);
        acc[mf][0] = __builtin_amdgcn_mfma_f32_16x16x32_bf16(af, cw[c][0], acc[mf][0], 0, 0, 0);
        acc[mf][1] = __builtin_amdgcn_mfma_f32_16x16x32_bf16(af, cw[c][1], acc[mf][1], 0, 0, 0);
      }
    }
  }

  if constexpr (EPI == 2){
    // scatter epilogue: inc[(b*NN + slot[tok])*D + col] += (C + b2) * gate
    __syncthreads();
    const int bb = bm0 >> 12;           // batch (BM divides 4096)
#pragma unroll
    for (int mf = 0; mf < MF; ++mf){
      float gr[4]; int sl[4];
#pragma unroll
      for (int r = 0; r < 4; ++r){
        const int row = mf*16 + kq*4 + r;
        gr[r] = gate_lds[row];
        sl[r] = slot_lds[row];
      }
#pragma unroll
      for (int j = 0; j < 2; ++j){
        const int col = colb2 + j*16 + fRow;
        const float bvx = b2[col];
#pragma unroll
        for (int r = 0; r < 4; ++r)
          atomicAdd(incp + ((size_t)(bb*NN + sl[r]))*D + col, (acc[mf][j][r] + bvx) * gr[r]);
      }
    }
  } else {
    // fused residual + LayerNorm (BM=32, rows complete across the 8 waves' cols)
    float vals[MF][2][4];
#pragma unroll
    for (int mf = 0; mf < MF; ++mf){
      const int row0 = mf*16 + kq*4;
#pragma unroll
      for (int j = 0; j < 2; ++j){
        const int col = colb2 + j*16 + fRow;
        const float bvx = b2[col];
#pragma unroll
        for (int r = 0; r < 4; ++r)
          vals[mf][j][r] = S[(size_t)(bm0 + row0 + r)*N2 + col] + acc[mf][j][r] + bvx;
      }
    }
    __syncthreads();
    float* red = (float*)smem;          // [BM rows][8 waves][2]
#pragma unroll
    for (int mf = 0; mf < MF; ++mf)
#pragma unroll
      for (int r = 0; r < 4; ++r){
        float s = 0.f, q = 0.f;
#pragma unroll
        for (int j = 0; j < 2; ++j){ s += vals[mf][j][r]; q += vals[mf][j][r]*vals[mf][j][r]; }
        s += __shfl_xor(s, 1); s += __shfl_xor(s, 2); s += __shfl_xor(s, 4); s += __shfl_xor(s, 8);
        q += __shfl_xor(q, 1); q += __shfl_xor(q, 2); q += __shfl_xor(q, 4); q += __shfl_xor(q, 8);
        if (fRow == 0){
          const int row = mf*16 + kq*4 + r;
          red[(row*8 + w)*2 + 0] = s;
          red[(row*8 + w)*2 + 1] = q;
        }
      }
    __syncthreads();
    float* mur = (float*)smem + BM*8*2;
    if (t < BM){
      float s = 0.f, q = 0.f;
      for (int w2 = 0; w2 < 8; w2++){ s += red[(t*8 + w2)*2]; q += red[(t*8 + w2)*2 + 1]; }
      const float mu = s * (1.f/256.f);
      const float var = q * (1.f/256.f) - mu*mu;
      mur[t*2] = mu; mur[t*2 + 1] = rsqrtf(var + 1e-5f);
    }
    __syncthreads();
#pragma unroll
    for (int mf = 0; mf < MF; ++mf){
      const int row0 = mf*16 + kq*4;
#pragma unroll
      for (int j = 0; j < 2; ++j){
        const int col = colb2 + j*16 + fRow;
        const float lw = lnw[col], lb = lnb[col];
#pragma unroll
        for (int r = 0; r < 4; ++r){
          const int row = row0 + r;
          ((float*)Cout)[(size_t)(bm0 + row)*N2 + col] =
              (vals[mf][j][r] - mur[row*2]) * mur[row*2 + 1] * lw + lb;
        }
      }
    }
  }
}

// fp32 routing GEMM + fused X bf16-packing (R19 config, kept)
__global__ __launch_bounds__(256) void route6_k(const float* __restrict__ X,
                                                const float* __restrict__ Wcat,
                                                int* __restrict__ slot_out,
                                                bf16* __restrict__ Xp)
{
  __shared__ float lds[64 * 84];        // 21504B
  float* Xs = lds;                      // [16][68]
  float* Ws = lds + 16 * 68;            // [16][80]
  float* Cs = lds;                      // [64][84] epilogue alias

  const int t = threadIdx.x;
  const int tok0 = blockIdx.x * 64;
  const int cq = t & 15;
  const int tg = t >> 4;                // 0..15 -> tokens tg*4..tg*4+3
  const int stok = t >> 2, skq = t & 3;

  const float* xsrc = X + (size_t)(tok0 + stok) * D + 4*skq;
  const int wrow0 = t / 20,        wc0 = t - wrow0*20;
  const int wrow1 = (256+t) / 20,  wc1 = (256+t) - wrow1*20;

  float accg[4][4] = {};
  float accs[4] = {};

  auto packw = [&](int tok, int k0, float4 v){
    const int ng = tok >> 4, f = tok & 15;
    const int kt = k0 >> 5, q = (k0 >> 3) & 3, e0 = k0 & 7;
    const size_t off = ((size_t)(ng*8 + kt)*64 + (f*4 + q))*8 + e0;
    ushort4 u;
    u.x = __bfloat16_as_ushort(__float2bfloat16(v.x));
    u.y = __bfloat16_as_ushort(__float2bfloat16(v.y));
    u.z = __bfloat16_as_ushort(__float2bfloat16(v.z));
    u.w = __bfloat16_as_ushort(__float2bfloat16(v.w));
    *reinterpret_cast<ushort4*>(Xp + off) = u;
  };

  float4 xr = *reinterpret_cast<const float4*>(xsrc);
  float4 wr0 = *reinterpret_cast<const float4*>(Wcat + (size_t)wrow0*80 + 4*wc0);
  float4 wr1;
  if (t < 64) wr1 = *reinterpret_cast<const float4*>(Wcat + (size_t)wrow1*80 + 4*wc1);

  for (int kt = 0; kt < 16; ++kt){
    __syncthreads();
    Xs[(4*skq+0)*68 + stok] = xr.x;
    Xs[(4*skq+1)*68 + stok] = xr.y;
    Xs[(4*skq+2)*68 + stok] = xr.z;
    Xs[(4*skq+3)*68 + stok] = xr.w;
    *reinterpret_cast<float4*>(&Ws[wrow0*80 + 4*wc0]) = wr0;
    if (t < 64) *reinterpret_cast<float4*>(&Ws[wrow1*80 + 4*wc1]) = wr1;
    packw(tok0 + stok, kt*16 + 4*skq, xr);
    __syncthreads();
    if (kt < 15){
      const int ko = (kt+1)*16;
      xr  = *reinterpret_cast<const float4*>(xsrc + ko);
      wr0 = *reinterpret_cast<const float4*>(Wcat + (size_t)(ko + wrow0)*80 + 4*wc0);
      if (t < 64) wr1 = *reinterpret_cast<const float4*>(Wcat + (size_t)(ko + wrow1)*80 + 4*wc1);
    }
#pragma unroll
    for (int k = 0; k < 16; ++k){
      const float4 xa = *reinterpret_cast<const float4*>(&Xs[k*68 + tg*4]);
      const float4 wq = *reinterpret_cast<const float4*>(&Ws[k*80 + 4*cq]);
      const float wsv = Ws[k*80 + 64 + cq];
      const float xv[4] = {xa.x, xa.y, xa.z, xa.w};
#pragma unroll
      for (int m = 0; m < 4; m++){
        accg[m][0] = fmaf(xv[m], wq.x, accg[m][0]);
        accg[m][1] = fmaf(xv[m], wq.y, accg[m][1]);
        accg[m][2] = fmaf(xv[m], wq.z, accg[m][2]);
        accg[m][3] = fmaf(xv[m], wq.w, accg[m][3]);
        accs[m]    = fmaf(xv[m], wsv,  accs[m]);
      }
    }
  }

  __syncthreads();
#pragma unroll
  for (int m = 0; m < 4; m++){
    const int tok = tg*4 + m;
    Cs[tok*84 + 4*cq + 0] = accg[m][0];
    Cs[tok*84 + 4*cq + 1] = accg[m][1];
    Cs[tok*84 + 4*cq + 2] = accg[m][2];
    Cs[tok*84 + 4*cq + 3] = accg[m][3];
    Cs[tok*84 + 64 + cq]  = accs[m];
  }
  __syncthreads();
  if (t < 64){
    const float* row = &Cs[t * 84];
    float bg = row[0]; int big = 0;
    for (int g = 1; g < 64; ++g){ const float v = row[g]; if (v > bg){ bg = v; big = g; } }
    float bs = row[64]; int bis = 0;
    for (int s2 = 1; s2 < 16; ++s2){ const float v = row[64 + s2]; if (v > bs){ bs = v; bis = s2; } }
    slot_out[tok0 + t] = big * KK + bis;
  }
}

} // namespace

extern "C" void kernel_launch(void* const* d_in, const int* in_sizes, int n_in,
                              void* d_out, int out_size, void* d_ws, size_t ws_size,
                              hipStream_t stream)
{
  (void)in_sizes; (void)n_in; (void)out_size; (void)ws_size;
  const float* X   = (const float*)d_in[0];
  const float* S   = (const float*)d_in[1];
  const float* Wgr = (const float*)d_in[2];
  const float* Wsl = (const float*)d_in[3];
  const float* Wm1 = (const float*)d_in[4];
  const float* bm1 = (const float*)d_in[5];
  const float* Wm2 = (const float*)d_in[6];
  const float* bm2 = (const float*)d_in[7];
  const float* Wg1 = (const float*)d_in[8];
  const float* bg1 = (const float*)d_in[9];
  const float* Wg2 = (const float*)d_in[10];
  const float* bg2 = (const float*)d_in[11];
  const float* Wu1 = (const float*)d_in[12];
  const float* bu1 = (const float*)d_in[13];
  const float* Wu2 = (const float*)d_in[14];
  const float* bu2 = (const float*)d_in[15];
  const float* lnw = (const float*)d_in[16];
  const float* lnb = (const float*)d_in[17];
  float* out = (float*)d_out;

  char* ws = (char*)d_ws;
  bf16* Xp   = (bf16*)(ws + 0);                   // 16,777,216 B (packed X)
  bf16* W1p  = (bf16*)(ws + 67108864);            // 393,216 B (packed [Wm1|Wg1], NK=8)
  bf16* W2p  = (bf16*)(ws + 67108864 + 393216);   // 262,144 B (packed Wm2, NK=16)
  bf16* Wu1p = (bf16*)(ws + 67108864 + 655360);   // 524,288 B (packed Wu1, NK=16)
  bf16* Wu2p = (bf16*)(ws + 67108864 + 1179648);  // 262,144 B (packed Wu2, NK=16)
  int*   slot = (int*)  (ws + 68550656);          // 131,072 B
  float* inc  = (float*)(ws + 68812800);          // 8,388,608 B
  float* Wcat = (float*)(ws + 77201408);          // 81,920 B
  float* bcat = (float*)(ws + 77201408 + 81920);  // 3,072 B

  prep_w_k<<<(742144 + 255)/256, 256, 0, stream>>>(Wm1, Wg1, Wm2, Wu1, Wu2, Wgr, Wsl, bm1, bg1,
                                                   W1p, W2p, Wu1p, Wu2p, Wcat, bcat);

  // routing + fused X bf16 packing (64 tokens/block, 2 blocks/CU)
  route6_k<<<NTOK/64, 256, 0, stream>>>(X, Wcat, slot, Xp);
  hipMemsetAsync(inc, 0, (size_t)NSLOT*D*sizeof(float), stream);

  // fused msg MLP + gate + scatter: inc[slot] += (gelu(X@Wm1+bm1)@Wm2+bm2) * sigmoid(gate)
  fused2_k<256, 512, 256, 256, 64, 2, 0><<<NTOK/64, 512, 0, stream>>>(
      Xp, W1p, bcat, W2p, bm2, nullptr,
      nullptr, nullptr, nullptr, Wg2, slot, bg2, inc);

  // fused slot-update MLP + residual + LayerNorm -> out
  fused2_k<512, 512, 0, 256, 32, 1, 1><<<NSLOT/32, 512, 0, stream>>>(
      nullptr, Wu1p, bu1, Wu2p, bu2, out,
      S, lnw, lnb, nullptr, nullptr, nullptr, inc);
}